// Round 11
// baseline (214.695 us; speedup 1.0000x reference)
//
#include <hip/hip_runtime.h>
#include <cstdint>
#include <math.h>

// ---------------------------------------------------------------------------
// Problem constants
//   B=8
//   level 1: fine xyz1 [8,2048,3], coarse xyz2 [8,512,3], x1 [8,256,2048], x2 [8,512,512]
//   level 2: fine xyz0 [8,8192,3], coarse xyz1 [8,2048,3], x0 [8,128,8192]
//   out [8, 896, 8192] f32
// 5-launch schedule (inter holds RAW level-1 interp; normalization deferred
// into write2 as a per-region affine alpha*v+beta):
//   L1 k_front         : knn2 | knn1 | copy0 | transB | transA
//                        (knn: 2 fine points per thread -> one LDS read feeds
//                         two distance comps; halves the LDS-issue pole)
//   L2 k_interp1_fused : gather pts1 -> raw inter[:, :, 256:768] + partials1
//   L3 k_interp_stats  : gather raw inter -> partials2 (per-cb region split)
//   L4 k_fin_combined  : double reduce + affine correction -> {a,b}x{lo,hi}
//   L5 k_interp2_write : gather raw inter, out = a*v + b (per c-block a,b)
// Rules learned: no per-block agent-scope fences/atomics in hot kernels (R7);
// LDS-staged knn beats uniform VMEM scan at this occupancy (R9).
// ---------------------------------------------------------------------------

// Merge 6 candidates (2 chunks x sorted top-3, chunk-major => ascending index
// order within equal distances; strict < keeps the earlier candidate, matching
// top_k tie-breaking). Weights = normalized inverse distances.
__device__ __forceinline__ void dev_merge6(const float* __restrict__ cd,
                                           const int* __restrict__ ci,
                                           int& o0, int& o1, int& o2,
                                           float& w0, float& w1, float& w2) {
    float d0 = 1e30f, d1 = 1e30f, d2 = 1e30f;
    int j0 = 0, j1 = 0, j2 = 0;
#pragma unroll
    for (int k = 0; k < 6; ++k) {
        const float d = cd[k];
        const int s = ci[k];
        const bool lt0 = d < d0, lt1 = d < d1, lt2 = d < d2;
        d2 = lt1 ? d1 : (lt2 ? d : d2);
        j2 = lt1 ? j1 : (lt2 ? s : j2);
        d1 = lt0 ? d0 : (lt1 ? d : d1);
        j1 = lt0 ? j0 : (lt1 ? s : j1);
        d0 = lt0 ? d : d0;
        j0 = lt0 ? s : j0;
    }
    const float a = 1.0f / (d0 + 1e-8f);
    const float b = 1.0f / (d1 + 1e-8f);
    const float c = 1.0f / (d2 + 1e-8f);
    const float ws = (a + b) + c;
    o0 = j0; o1 = j1; o2 = j2;
    w0 = a / ws; w1 = b / ws; w2 = c / ws;
}

// kNN chunk scan, 2 fine points per thread, coarse chunk staged in LDS.
// One ds_read_b128 per iteration feeds BOTH points' distance computations.
// Distance form bit-matches reference: fmaf(-2,dot,psq+cw) == (psq+cw)-2*dot.
// Block covers 512 fine points: point A = base+tid, point B = base+256+tid.
template <int CHUNK>
__device__ __forceinline__ void dev_knn_lds2(const float* __restrict__ fine,
                                             const float* __restrict__ coarse,
                                             int N, int S, int nch,
                                             int b, int nb, int chunk, int tid,
                                             float4* __restrict__ lc,
                                             float* __restrict__ cand_d,
                                             int* __restrict__ cand_i) {
#pragma clang fp contract(off)
    const int s0 = chunk * CHUNK;
    const float* cb = coarse + ((size_t)b * S + s0) * 3;
    for (int s = tid; s < CHUNK; s += 256) {
        const float x = cb[3 * s], y = cb[3 * s + 1], z = cb[3 * s + 2];
        lc[s] = make_float4(x, y, z, (x * x + y * y) + z * z);
    }
    __syncthreads();
    const int na = nb * 512 + tid;
    const int nbp = na + 256;
    const float* fa = fine + ((size_t)b * N + na) * 3;
    const float* fb = fine + ((size_t)b * N + nbp) * 3;
    const float pax = fa[0], pay = fa[1], paz = fa[2];
    const float pbx = fb[0], pby = fb[1], pbz = fb[2];
    const float psqa = (pax * pax + pay * pay) + paz * paz;
    const float psqb = (pbx * pbx + pby * pby) + pbz * pbz;
    float da0 = 1e30f, da1 = 1e30f, da2 = 1e30f;
    float db0 = 1e30f, db1 = 1e30f, db2 = 1e30f;
    int ia0 = 0, ia1 = 0, ia2 = 0;
    int ib0 = 0, ib1 = 0, ib2 = 0;
#pragma unroll 4
    for (int s = 0; s < CHUNK; ++s) {
        const float4 c = lc[s];
        const float dota = (pax * c.x + pay * c.y) + paz * c.z;
        const float dotb = (pbx * c.x + pby * c.y) + pbz * c.z;
        const float da = fmaf(-2.0f, dota, psqa + c.w);
        const float db = fmaf(-2.0f, dotb, psqb + c.w);
        if (__any((da < da2) || (db < db2))) {
            {
                const bool lt0 = da < da0, lt1 = da < da1, lt2 = da < da2;
                da2 = lt1 ? da1 : (lt2 ? da : da2);
                ia2 = lt1 ? ia1 : (lt2 ? s : ia2);
                da1 = lt0 ? da0 : (lt1 ? da : da1);
                ia1 = lt0 ? ia0 : (lt1 ? s : ia1);
                da0 = lt0 ? da : da0;
                ia0 = lt0 ? s : ia0;
            }
            {
                const bool lt0 = db < db0, lt1 = db < db1, lt2 = db < db2;
                db2 = lt1 ? db1 : (lt2 ? db : db2);
                ib2 = lt1 ? ib1 : (lt2 ? s : ib2);
                db1 = lt0 ? db0 : (lt1 ? db : db1);
                ib1 = lt0 ? ib0 : (lt1 ? s : ib1);
                db0 = lt0 ? db : db0;
                ib0 = lt0 ? s : ib0;
            }
        }
    }
    const size_t pa = (((size_t)b * N + na) * nch + chunk) * 3;
    cand_d[pa] = da0; cand_d[pa + 1] = da1; cand_d[pa + 2] = da2;
    cand_i[pa] = s0 + ia0; cand_i[pa + 1] = s0 + ia1; cand_i[pa + 2] = s0 + ia2;
    const size_t pb = (((size_t)b * N + nbp) * nch + chunk) * 3;
    cand_d[pb] = db0; cand_d[pb + 1] = db1; cand_d[pb + 2] = db2;
    cand_i[pb] = s0 + ib0; cand_i[pb + 1] = s0 + ib1; cand_i[pb + 2] = s0 + ib2;
}

__device__ __forceinline__ void dev_transpose(const float* __restrict__ in,
                                              float* __restrict__ out,
                                              int C, long in_bs, long out_bs, int out_rs,
                                              int b, int rt, int ct, int tid,
                                              float* __restrict__ tile /*[32][33]*/) {
    const int r0 = rt * 32, c0 = ct * 32;
    const float* inb = in + (size_t)b * in_bs;
    float* outb = out + (size_t)b * out_bs;
    const int tx = tid & 31, ty = tid >> 5;   // 32 x 8
#pragma unroll
    for (int i = 0; i < 32; i += 8) {
        tile[(ty + i) * 33 + tx] = inb[(size_t)(r0 + ty + i) * C + (c0 + tx)];
    }
    __syncthreads();
#pragma unroll
    for (int i = 0; i < 32; i += 8) {
        outb[(size_t)(c0 + ty + i) * out_rs + (r0 + tx)] = tile[tx * 33 + (ty + i)];
    }
}

// L1: fused front. Blocks:
//   [0,256)        knn level 2 (CHUNK=1024, nch=2, 512 pts/block):
//                  b=id>>5, nb=(id&31)&15, chunk=(id>>4)&1
//   [256,320)      knn level 1 (CHUNK=256,  nch=2, 512 pts/block):
//                  t=id-256: b=t>>3, nb=t&3, chunk=(t>>2)&1
//   [320,8512)     copy0  x0 -> out[:,0:128,:]
//   [8512,12608)   transB x1 [8,256,2048] -> inter[b][c][r] (rs=768)
//   [12608,14656)  transA x2 [8,512,512]  -> pts1 (rs=512)
// knn blocks first: they are the VALU/LDS pole; HBM-bound blocks backfill.
__global__ __launch_bounds__(256) void k_front(const float* __restrict__ xyz0,
                                               const float* __restrict__ xyz1,
                                               const float* __restrict__ xyz2,
                                               const float* __restrict__ x0,
                                               const float* __restrict__ x1,
                                               const float* __restrict__ x2,
                                               float* __restrict__ pts1,
                                               float* __restrict__ inter,
                                               float* __restrict__ out,
                                               float* __restrict__ cand_d2,
                                               int* __restrict__ cand_i2,
                                               float* __restrict__ cand_d1,
                                               int* __restrict__ cand_i1) {
    __shared__ __align__(16) char smem[16384];   // union: lc (16K) | tile (4.2K)
    const int id = blockIdx.x;
    const int tid = threadIdx.x;
    if (id < 256) {
        const int r = id & 31;
        dev_knn_lds2<1024>(xyz0, xyz1, 8192, 2048, 2,
                           id >> 5, r & 15, (r >> 4) & 1, tid,
                           (float4*)smem, cand_d2, cand_i2);
    } else if (id < 320) {
        const int t = id - 256;
        dev_knn_lds2<256>(xyz1, xyz2, 2048, 512, 2,
                          t >> 3, t & 3, (t >> 2) & 1, tid,
                          (float4*)smem, cand_d1, cand_i1);
    } else if (id < 8512) {                      // copy0
        const size_t i = (size_t)(id - 320) * 256 + tid;
        const size_t b = i >> 18;
        const size_t off = i & (((size_t)1 << 18) - 1);
        const float4* src = (const float4*)(x0 + b * (size_t)128 * 8192);
        float4* dst = (float4*)(out + b * (size_t)896 * 8192);
        dst[off] = src[off];
    } else if (id < 12608) {                     // transB
        const int t = id - 8512;
        const int ct = t & 63, rt = (t >> 6) & 7, b = t >> 9;
        dev_transpose(x1, inter, 2048, 256 * 2048, (long)2048 * 768, 768,
                      b, rt, ct, tid, (float*)smem);
    } else {                                     // transA
        const int t = id - 12608;
        const int ct = t & 15, rt = (t >> 4) & 15, b = t >> 8;
        dev_transpose(x2, pts1, 512, 512 * 512, 512 * 512, 512,
                      b, rt, ct, tid, (float*)smem);
    }
}

// L2: level-1 fused gather: write RAW interp to inter[:, :, 256:768] and
// accumulate double partials. Grid (x=8, y=128); 16 points/block.
__global__ __launch_bounds__(256) void k_interp1_fused(const float* __restrict__ pts,
                                                       const float* __restrict__ cand_d,
                                                       const int* __restrict__ cand_i,
                                                       float* __restrict__ inter,
                                                       double* __restrict__ partials1) {
    __shared__ int   si[16][3];
    __shared__ float sw[16][3];
    const int b = blockIdx.x, nb = blockIdx.y;
    const int n0 = nb * 16;
    const int tid = threadIdx.x;
    if (tid < 16) {
        const size_t pt = (size_t)b * 2048 + n0 + tid;
        dev_merge6(cand_d + pt * 6, cand_i + pt * 6,
                   si[tid][0], si[tid][1], si[tid][2],
                   sw[tid][0], sw[tid][1], sw[tid][2]);
    }
    __syncthreads();
    const float4* pb4 = (const float4*)(pts + (size_t)b * 512 * 512);
    const int pg = tid >> 6, f = tid & 63;
    double ls = 0.0, lq = 0.0;
#pragma unroll
    for (int g = 0; g < 4; ++g) {
        const int pl = g * 4 + pg;
        const size_t p = (size_t)b * 2048 + n0 + pl;
        const size_t r0 = (size_t)si[pl][0] * 128;
        const size_t r1 = (size_t)si[pl][1] * 128;
        const size_t r2 = (size_t)si[pl][2] * 128;
        const float w0 = sw[pl][0], w1 = sw[pl][1], w2 = sw[pl][2];
        float4* out4 = (float4*)(inter + p * 768 + 256);
#pragma unroll
        for (int k = 0; k < 2; ++k) {
            const int c = f + k * 64;
            const float4 a = pb4[r0 + c], d = pb4[r1 + c], e = pb4[r2 + c];
            float4 v;
            v.x = (w0 * a.x + w1 * d.x) + w2 * e.x;
            v.y = (w0 * a.y + w1 * d.y) + w2 * e.y;
            v.z = (w0 * a.z + w1 * d.z) + w2 * e.z;
            v.w = (w0 * a.w + w1 * d.w) + w2 * e.w;
            out4[c] = v;
            ls += (double)v.x + (double)v.y + (double)v.z + (double)v.w;
            lq += (double)v.x * v.x + (double)v.y * v.y
                + (double)v.z * v.z + (double)v.w * v.w;
        }
    }
    __shared__ double sa[256], sb[256];
    sa[tid] = ls; sb[tid] = lq; __syncthreads();
    for (int s = 128; s > 0; s >>= 1) {
        if (tid < s) { sa[tid] += sa[tid + s]; sb[tid] += sb[tid + s]; }
        __syncthreads();
    }
    if (tid == 0) {
        const size_t pl = (size_t)b * gridDim.y + nb;
        partials1[2 * pl] = sa[0]; partials1[2 * pl + 1] = sb[0];
    }
}

// L3: stats gather over raw inter; per-block double partials, cb-major layout
// so the finalize can split c<256 (cb=0) from c>=256 (cb=1,2).
// Grid (x=B, y=N/32, z=C/256); blockIdx.x = batch -> XCD-pinned L2 reuse.
__global__ __launch_bounds__(256) void k_interp_stats(const float* __restrict__ pts,
                                                      const float* __restrict__ cand_d,
                                                      const int* __restrict__ cand_i,
                                                      int N, int S, int C,
                                                      double* __restrict__ partials) {
    __shared__ int   si[32][3];
    __shared__ float sw[32][3];
    const int b = blockIdx.x, nb = blockIdx.y, cb = blockIdx.z;
    const int n0 = nb * 32;
    const int tid = threadIdx.x;
    if (tid < 32) {
        const size_t pt = (size_t)b * N + n0 + tid;
        dev_merge6(cand_d + pt * 6, cand_i + pt * 6,
                   si[tid][0], si[tid][1], si[tid][2],
                   sw[tid][0], sw[tid][1], sw[tid][2]);
    }
    __syncthreads();
    const int C4 = C >> 2;
    const float4* pbf = (const float4*)(pts + (size_t)b * S * C) + (cb * 64);
    const int f = tid & 63;
    const int pg = tid >> 6;
    double ls = 0.0, lq = 0.0;
#pragma unroll
    for (int g = 0; g < 8; ++g) {
        const int nl = g * 4 + pg;
        const size_t r0 = (size_t)si[nl][0] * C4;
        const size_t r1 = (size_t)si[nl][1] * C4;
        const size_t r2 = (size_t)si[nl][2] * C4;
        const float w0 = sw[nl][0], w1 = sw[nl][1], w2 = sw[nl][2];
        const float4 a = pbf[r0 + f], c = pbf[r1 + f], e = pbf[r2 + f];
        const float vx = (w0 * a.x + w1 * c.x) + w2 * e.x;
        const float vy = (w0 * a.y + w1 * c.y) + w2 * e.y;
        const float vz = (w0 * a.z + w1 * c.z) + w2 * e.z;
        const float vw = (w0 * a.w + w1 * c.w) + w2 * e.w;
        ls += (double)vx + (double)vy + (double)vz + (double)vw;
        lq += (double)vx * vx + (double)vy * vy + (double)vz * vz + (double)vw * vw;
    }
    __shared__ double sa[256], sb[256];
    sa[tid] = ls; sb[tid] = lq; __syncthreads();
    for (int s = 128; s > 0; s >>= 1) {
        if (tid < s) { sa[tid] += sa[tid + s]; sb[tid] += sb[tid + s]; }
        __syncthreads();
    }
    if (tid == 0) {
        const size_t pl = ((size_t)cb * gridDim.x + b) * gridDim.y + nb;
        partials[2 * pl] = sa[0]; partials[2 * pl + 1] = sb[0];
    }
}

// L4: combined finalize (1 block). Emits stats4 = {alpha_lo, beta_lo,
// alpha_hi, beta_hi}: out = alpha*v_raw + beta == (v_final - m2) * rs2.
__global__ __launch_bounds__(256) void k_fin_combined(const double* __restrict__ partials1,
                                                      int P1,
                                                      const double* __restrict__ partials2,
                                                      int P2, int P2lo,
                                                      float* __restrict__ stats4) {
    __shared__ double red[6][256];
    const int t = threadIdx.x;
    double s1 = 0.0, q1 = 0.0, s2l = 0.0, q2l = 0.0, s2h = 0.0, q2h = 0.0;
    for (int i = t; i < P1; i += 256) { s1 += partials1[2 * i]; q1 += partials1[2 * i + 1]; }
    for (int i = t; i < P2; i += 256) {
        const double s = partials2[2 * i], q = partials2[2 * i + 1];
        if (i < P2lo) { s2l += s; q2l += q; } else { s2h += s; q2h += q; }
    }
    red[0][t] = s1; red[1][t] = q1; red[2][t] = s2l;
    red[3][t] = q2l; red[4][t] = s2h; red[5][t] = q2h;
    __syncthreads();
    for (int s = 128; s > 0; s >>= 1) {
        if (t < s) {
#pragma unroll
            for (int r = 0; r < 6; ++r) red[r][t] += red[r][t + s];
        }
        __syncthreads();
    }
    if (t == 0) {
        const double nelem1 = 8388608.0;      // 8*2048*512
        const double cnt2   = 50331648.0;     // 8*8192*768
        const double cnthi  = 33554432.0;     // 8*8192*512
        const double S1 = red[0][0], Q1 = red[1][0];
        const double m1 = S1 / nelem1;
        const double v1 = (Q1 - S1 * S1 / nelem1) / (nelem1 - 1.0);
        const double sd1 = sqrt(v1 > 0.0 ? v1 : 0.0);
        const float rs1f = (float)(1.0 / (sd1 + 1e-5));
        const float m1f = (float)m1;
        const double a1 = (double)rs1f;
        const double b1 = -(double)m1f * (double)rs1f;
        const double S2l = red[2][0], Q2l = red[3][0];
        const double S2h = red[4][0], Q2h = red[5][0];
        const double Sf = S2l + a1 * S2h + b1 * cnthi;
        const double Qf = Q2l + a1 * a1 * Q2h + 2.0 * a1 * b1 * S2h + b1 * b1 * cnthi;
        const double m2 = Sf / cnt2;
        const double v2 = (Qf - Sf * Sf / cnt2) / (cnt2 - 1.0);
        const double sd2 = sqrt(v2 > 0.0 ? v2 : 0.0);
        const double rs2 = 1.0 / (sd2 + 1e-5);
        stats4[0] = (float)rs2;                 // alpha_lo (c < 256)
        stats4[1] = (float)(-m2 * rs2);         // beta_lo
        stats4[2] = (float)(a1 * rs2);          // alpha_hi (c >= 256)
        stats4[3] = (float)((b1 - m2) * rs2);   // beta_hi
    }
}

// L5: level-2 write pass: grid (x=B, y=128 n-tiles, z=12 c-blocks). Gather raw
// inter rows, apply per-region affine, write TRANSPOSED via 64x64 LDS tile.
__global__ __launch_bounds__(256) void k_interp2_write(const float* __restrict__ pts,
                                                       const float* __restrict__ cand_d,
                                                       const int* __restrict__ cand_i,
                                                       const float* __restrict__ stats4,
                                                       float* __restrict__ out) {
    __shared__ float tile[64][65];
    __shared__ int   si[64][3];
    __shared__ float sw[64][3];
    const int b = blockIdx.x, nt = blockIdx.y, cc = blockIdx.z;
    const float alpha = (cc < 4) ? stats4[0] : stats4[2];
    const float beta  = (cc < 4) ? stats4[1] : stats4[3];
    const int n0 = nt * 64, c0 = cc * 64;
    const int tid = threadIdx.x;
    if (tid < 64) {
        const size_t pt = (size_t)b * 8192 + n0 + tid;
        dev_merge6(cand_d + pt * 6, cand_i + pt * 6,
                   si[tid][0], si[tid][1], si[tid][2],
                   sw[tid][0], sw[tid][1], sw[tid][2]);
    }
    __syncthreads();
    const float* pb = pts + (size_t)b * 2048 * 768 + c0;
    const int cl = tid & 63;
    const int pg = tid >> 6;
#pragma unroll
    for (int pass = 0; pass < 16; ++pass) {
        const int nl = pass * 4 + pg;
        const float v = (sw[nl][0] * pb[(size_t)si[nl][0] * 768 + cl]
                       + sw[nl][1] * pb[(size_t)si[nl][1] * 768 + cl])
                       + sw[nl][2] * pb[(size_t)si[nl][2] * 768 + cl];
        tile[nl][cl] = alpha * v + beta;
    }
    __syncthreads();
    float* ob = out + (size_t)b * 896 * 8192 + (size_t)(128 + c0) * 8192 + n0;
    const int tn = tid & 63, tc0 = tid >> 6;
#pragma unroll
    for (int pass = 0; pass < 16; ++pass) {
        const int tc = pass * 4 + tc0;
        ob[(size_t)tc * 8192 + tn] = tile[tn][tc];
    }
}

extern "C" void kernel_launch(void* const* d_in, const int* in_sizes, int n_in,
                              void* d_out, int out_size, void* d_ws, size_t ws_size,
                              hipStream_t stream) {
    const float* xyz0 = (const float*)d_in[0];
    const float* xyz1 = (const float*)d_in[1];
    const float* xyz2 = (const float*)d_in[2];
    const float* x0   = (const float*)d_in[3];
    const float* x1   = (const float*)d_in[4];
    const float* x2   = (const float*)d_in[5];
    float* out = (float*)d_out;
    char* ws = (char*)d_ws;

    size_t off = 0;
    auto alloc = [&](size_t bytes) {
        size_t o = off;
        off = (off + bytes + 255) & ~(size_t)255;
        return o;
    };
    float*  stats4    = (float*)(ws + alloc(4 * sizeof(float)));
    double* partials1 = (double*)(ws + alloc((size_t)1024 * 2 * sizeof(double)));
    double* partials2 = (double*)(ws + alloc((size_t)6144 * 2 * sizeof(double)));
    float*  pts1      = (float*)(ws + alloc((size_t)8 * 512 * 512 * 4));   // x2^T
    float*  inter     = (float*)(ws + alloc((size_t)8 * 2048 * 768 * 4));  // RAW [8,2048,768]
    float*  cand_d2   = (float*)(ws + alloc((size_t)65536 * 6 * 4));
    int*    cand_i2   = (int*)(ws + alloc((size_t)65536 * 6 * 4));
    float*  cand_d1   = (float*)(ws + alloc((size_t)16384 * 6 * 4));
    int*    cand_i1   = (int*)(ws + alloc((size_t)16384 * 6 * 4));

    // L1: knn2 | knn1 | copy0 | transB | transA
    k_front<<<14656, 256, 0, stream>>>(xyz0, xyz1, xyz2, x0, x1, x2,
                                       pts1, inter, out,
                                       cand_d2, cand_i2, cand_d1, cand_i1);
    // L2: level-1 fused raw write + partials1
    k_interp1_fused<<<dim3(8, 128), 256, 0, stream>>>(
        pts1, cand_d1, cand_i1, inter, partials1);
    // L3: level-2 raw stats -> partials2 (cb-major: first 2048 = c<256)
    k_interp_stats<<<dim3(8, 256, 3), 256, 0, stream>>>(
        inter, cand_d2, cand_i2, 8192, 2048, 768, partials2);
    // L4: combined finalize -> stats4
    k_fin_combined<<<1, 256, 0, stream>>>(partials1, 1024, partials2, 6144, 2048, stats4);
    // L5: level-2 write with per-region affine
    k_interp2_write<<<dim3(8, 128, 12), 256, 0, stream>>>(inter, cand_d2, cand_i2,
                                                          stats4, out);
}

// Round 12
// 188.288 us; speedup vs baseline: 1.1402x; 1.1402x over previous
//
#include <hip/hip_runtime.h>
#include <cstdint>
#include <math.h>

// ---------------------------------------------------------------------------
// Problem constants
//   B=8
//   level 1: fine xyz1 [8,2048,3], coarse xyz2 [8,512,3], x1 [8,256,2048], x2 [8,512,512]
//   level 2: fine xyz0 [8,8192,3], coarse xyz1 [8,2048,3], x0 [8,128,8192]
//   out [8, 896, 8192] f32
// 5-launch schedule (inter holds RAW level-1 interp; normalization deferred
// into write2 as a per-region affine alpha*v+beta):
//   L1 k_front         : knn2 | knn1 | copy0 | transB | transA  (R10 structure)
//   L2 k_interp1_fused : gather pts1 -> raw inter[:, :, 256:768] + partials1
//   L3 k_interp_stats  : gather raw inter -> partials2 (per-cb region split)
//   L4 k_fin_combined  : double reduce + affine correction -> {a,b}x{lo,hi}
//   L5 k_interp2_write : gather raw inter, out = a*v + b (per c-block a,b)
// Rules learned:
//   - no per-block agent-scope fences/atomics in hot kernels (R7)
//   - LDS-staged knn beats uniform VMEM scan at this occupancy (R9)
//   - knn scan needs >=2 waves/SIMD; 1 pt/thread, 512 blocks is optimal (R11)
// ---------------------------------------------------------------------------

// Merge 6 candidates (2 chunks x sorted top-3, chunk-major => ascending index
// order within equal distances; strict < keeps the earlier candidate, matching
// top_k tie-breaking). Weights = normalized inverse distances.
__device__ __forceinline__ void dev_merge6(const float* __restrict__ cd,
                                           const int* __restrict__ ci,
                                           int& o0, int& o1, int& o2,
                                           float& w0, float& w1, float& w2) {
    float d0 = 1e30f, d1 = 1e30f, d2 = 1e30f;
    int j0 = 0, j1 = 0, j2 = 0;
#pragma unroll
    for (int k = 0; k < 6; ++k) {
        const float d = cd[k];
        const int s = ci[k];
        const bool lt0 = d < d0, lt1 = d < d1, lt2 = d < d2;
        d2 = lt1 ? d1 : (lt2 ? d : d2);
        j2 = lt1 ? j1 : (lt2 ? s : j2);
        d1 = lt0 ? d0 : (lt1 ? d : d1);
        j1 = lt0 ? j0 : (lt1 ? s : j1);
        d0 = lt0 ? d : d0;
        j0 = lt0 ? s : j0;
    }
    const float a = 1.0f / (d0 + 1e-8f);
    const float b = 1.0f / (d1 + 1e-8f);
    const float c = 1.0f / (d2 + 1e-8f);
    const float ws = (a + b) + c;
    o0 = j0; o1 = j1; o2 = j2;
    w0 = a / ws; w1 = b / ws; w2 = c / ws;
}

// kNN chunk scan with inline LDS pack of the coarse chunk. 1 point/thread.
// Distance form bit-matches reference: fmaf(-2,dot,psq+cw) == (psq+cw)-2*dot.
// unroll 8: keep ~8 ds_read_b128 in flight per wave to hide LDS latency at
// the ~2 waves/SIMD occupancy this kernel runs at.
template <int CHUNK>
__device__ __forceinline__ void dev_knn_lds(const float* __restrict__ fine,
                                            const float* __restrict__ coarse,
                                            int N, int S, int nch,
                                            int b, int nb, int chunk, int tid,
                                            float4* __restrict__ lc,
                                            float* __restrict__ cand_d,
                                            int* __restrict__ cand_i) {
#pragma clang fp contract(off)
    const int s0 = chunk * CHUNK;
    const float* cb = coarse + ((size_t)b * S + s0) * 3;
    for (int s = tid; s < CHUNK; s += 256) {
        const float x = cb[3 * s], y = cb[3 * s + 1], z = cb[3 * s + 2];
        lc[s] = make_float4(x, y, z, (x * x + y * y) + z * z);
    }
    __syncthreads();
    const int n = nb * 256 + tid;
    const float* fp = fine + ((size_t)b * N + n) * 3;
    const float px = fp[0], py = fp[1], pz = fp[2];
    const float psq = (px * px + py * py) + pz * pz;
    float d0 = 1e30f, d1 = 1e30f, d2 = 1e30f;
    int i0 = 0, i1 = 0, i2 = 0;
#pragma unroll 8
    for (int s = 0; s < CHUNK; ++s) {
        const float4 c = lc[s];
        const float dot = (px * c.x + py * c.y) + pz * c.z;
        const float d = fmaf(-2.0f, dot, psq + c.w);
        if (__any(d < d2)) {
            const bool lt0 = d < d0, lt1 = d < d1, lt2 = d < d2;
            d2 = lt1 ? d1 : (lt2 ? d : d2);
            i2 = lt1 ? i1 : (lt2 ? s : i2);
            d1 = lt0 ? d0 : (lt1 ? d : d1);
            i1 = lt0 ? i0 : (lt1 ? s : i1);
            d0 = lt0 ? d : d0;
            i0 = lt0 ? s : i0;
        }
    }
    const size_t p = (((size_t)b * N + n) * nch + chunk) * 3;
    cand_d[p] = d0; cand_d[p + 1] = d1; cand_d[p + 2] = d2;
    cand_i[p] = s0 + i0; cand_i[p + 1] = s0 + i1; cand_i[p + 2] = s0 + i2;
}

__device__ __forceinline__ void dev_transpose(const float* __restrict__ in,
                                              float* __restrict__ out,
                                              int C, long in_bs, long out_bs, int out_rs,
                                              int b, int rt, int ct, int tid,
                                              float* __restrict__ tile /*[32][33]*/) {
    const int r0 = rt * 32, c0 = ct * 32;
    const float* inb = in + (size_t)b * in_bs;
    float* outb = out + (size_t)b * out_bs;
    const int tx = tid & 31, ty = tid >> 5;   // 32 x 8
#pragma unroll
    for (int i = 0; i < 32; i += 8) {
        tile[(ty + i) * 33 + tx] = inb[(size_t)(r0 + ty + i) * C + (c0 + tx)];
    }
    __syncthreads();
#pragma unroll
    for (int i = 0; i < 32; i += 8) {
        outb[(size_t)(c0 + ty + i) * out_rs + (r0 + tx)] = tile[tx * 33 + (ty + i)];
    }
}

// L1: fused front (R10 structure). Blocks:
//   [0,512)        knn level 2 (CHUNK=1024, nch=2): b=id>>6, nb=id&31, chunk=(id>>5)&1
//   [512,640)      knn level 1 (CHUNK=256,  nch=2): t=id-512: b=t>>4, nb=t&7, chunk=(t>>3)&1
//   [640,8832)     copy0  x0 -> out[:,0:128,:]
//   [8832,12928)   transB x1 [8,256,2048] -> inter[b][c][r] (rs=768)
//   [12928,14976)  transA x2 [8,512,512]  -> pts1 (rs=512)
__global__ __launch_bounds__(256) void k_front(const float* __restrict__ xyz0,
                                               const float* __restrict__ xyz1,
                                               const float* __restrict__ xyz2,
                                               const float* __restrict__ x0,
                                               const float* __restrict__ x1,
                                               const float* __restrict__ x2,
                                               float* __restrict__ pts1,
                                               float* __restrict__ inter,
                                               float* __restrict__ out,
                                               float* __restrict__ cand_d2,
                                               int* __restrict__ cand_i2,
                                               float* __restrict__ cand_d1,
                                               int* __restrict__ cand_i1) {
    __shared__ __align__(16) char smem[16384];   // union: lc (16K) | tile (4.2K)
    const int id = blockIdx.x;
    const int tid = threadIdx.x;
    if (id < 512) {
        dev_knn_lds<1024>(xyz0, xyz1, 8192, 2048, 2,
                          id >> 6, id & 31, (id >> 5) & 1, tid,
                          (float4*)smem, cand_d2, cand_i2);
    } else if (id < 640) {
        const int t = id - 512;
        dev_knn_lds<256>(xyz1, xyz2, 2048, 512, 2,
                         t >> 4, t & 7, (t >> 3) & 1, tid,
                         (float4*)smem, cand_d1, cand_i1);
    } else if (id < 8832) {                      // copy0
        const size_t i = (size_t)(id - 640) * 256 + tid;
        const size_t b = i >> 18;
        const size_t off = i & (((size_t)1 << 18) - 1);
        const float4* src = (const float4*)(x0 + b * (size_t)128 * 8192);
        float4* dst = (float4*)(out + b * (size_t)896 * 8192);
        dst[off] = src[off];
    } else if (id < 12928) {                     // transB
        const int t = id - 8832;
        const int ct = t & 63, rt = (t >> 6) & 7, b = t >> 9;
        dev_transpose(x1, inter, 2048, 256 * 2048, (long)2048 * 768, 768,
                      b, rt, ct, tid, (float*)smem);
    } else {                                     // transA
        const int t = id - 12928;
        const int ct = t & 15, rt = (t >> 4) & 15, b = t >> 8;
        dev_transpose(x2, pts1, 512, 512 * 512, 512 * 512, 512,
                      b, rt, ct, tid, (float*)smem);
    }
}

// L2: level-1 fused gather: write RAW interp to inter[:, :, 256:768] and
// accumulate double partials. Grid (x=8, y=128); 16 points/block.
__global__ __launch_bounds__(256) void k_interp1_fused(const float* __restrict__ pts,
                                                       const float* __restrict__ cand_d,
                                                       const int* __restrict__ cand_i,
                                                       float* __restrict__ inter,
                                                       double* __restrict__ partials1) {
    __shared__ int   si[16][3];
    __shared__ float sw[16][3];
    const int b = blockIdx.x, nb = blockIdx.y;
    const int n0 = nb * 16;
    const int tid = threadIdx.x;
    if (tid < 16) {
        const size_t pt = (size_t)b * 2048 + n0 + tid;
        dev_merge6(cand_d + pt * 6, cand_i + pt * 6,
                   si[tid][0], si[tid][1], si[tid][2],
                   sw[tid][0], sw[tid][1], sw[tid][2]);
    }
    __syncthreads();
    const float4* pb4 = (const float4*)(pts + (size_t)b * 512 * 512);
    const int pg = tid >> 6, f = tid & 63;
    double ls = 0.0, lq = 0.0;
#pragma unroll
    for (int g = 0; g < 4; ++g) {
        const int pl = g * 4 + pg;
        const size_t p = (size_t)b * 2048 + n0 + pl;
        const size_t r0 = (size_t)si[pl][0] * 128;
        const size_t r1 = (size_t)si[pl][1] * 128;
        const size_t r2 = (size_t)si[pl][2] * 128;
        const float w0 = sw[pl][0], w1 = sw[pl][1], w2 = sw[pl][2];
        float4* out4 = (float4*)(inter + p * 768 + 256);
#pragma unroll
        for (int k = 0; k < 2; ++k) {
            const int c = f + k * 64;
            const float4 a = pb4[r0 + c], d = pb4[r1 + c], e = pb4[r2 + c];
            float4 v;
            v.x = (w0 * a.x + w1 * d.x) + w2 * e.x;
            v.y = (w0 * a.y + w1 * d.y) + w2 * e.y;
            v.z = (w0 * a.z + w1 * d.z) + w2 * e.z;
            v.w = (w0 * a.w + w1 * d.w) + w2 * e.w;
            out4[c] = v;
            ls += (double)v.x + (double)v.y + (double)v.z + (double)v.w;
            lq += (double)v.x * v.x + (double)v.y * v.y
                + (double)v.z * v.z + (double)v.w * v.w;
        }
    }
    __shared__ double sa[256], sb[256];
    sa[tid] = ls; sb[tid] = lq; __syncthreads();
    for (int s = 128; s > 0; s >>= 1) {
        if (tid < s) { sa[tid] += sa[tid + s]; sb[tid] += sb[tid + s]; }
        __syncthreads();
    }
    if (tid == 0) {
        const size_t pl = (size_t)b * gridDim.y + nb;
        partials1[2 * pl] = sa[0]; partials1[2 * pl + 1] = sb[0];
    }
}

// L3: stats gather over raw inter; per-block double partials, cb-major layout
// so the finalize can split c<256 (cb=0) from c>=256 (cb=1,2).
// Grid (x=B, y=N/32, z=C/256); blockIdx.x = batch -> XCD-pinned L2 reuse.
__global__ __launch_bounds__(256) void k_interp_stats(const float* __restrict__ pts,
                                                      const float* __restrict__ cand_d,
                                                      const int* __restrict__ cand_i,
                                                      int N, int S, int C,
                                                      double* __restrict__ partials) {
    __shared__ int   si[32][3];
    __shared__ float sw[32][3];
    const int b = blockIdx.x, nb = blockIdx.y, cb = blockIdx.z;
    const int n0 = nb * 32;
    const int tid = threadIdx.x;
    if (tid < 32) {
        const size_t pt = (size_t)b * N + n0 + tid;
        dev_merge6(cand_d + pt * 6, cand_i + pt * 6,
                   si[tid][0], si[tid][1], si[tid][2],
                   sw[tid][0], sw[tid][1], sw[tid][2]);
    }
    __syncthreads();
    const int C4 = C >> 2;
    const float4* pbf = (const float4*)(pts + (size_t)b * S * C) + (cb * 64);
    const int f = tid & 63;
    const int pg = tid >> 6;
    double ls = 0.0, lq = 0.0;
#pragma unroll
    for (int g = 0; g < 8; ++g) {
        const int nl = g * 4 + pg;
        const size_t r0 = (size_t)si[nl][0] * C4;
        const size_t r1 = (size_t)si[nl][1] * C4;
        const size_t r2 = (size_t)si[nl][2] * C4;
        const float w0 = sw[nl][0], w1 = sw[nl][1], w2 = sw[nl][2];
        const float4 a = pbf[r0 + f], c = pbf[r1 + f], e = pbf[r2 + f];
        const float vx = (w0 * a.x + w1 * c.x) + w2 * e.x;
        const float vy = (w0 * a.y + w1 * c.y) + w2 * e.y;
        const float vz = (w0 * a.z + w1 * c.z) + w2 * e.z;
        const float vw = (w0 * a.w + w1 * c.w) + w2 * e.w;
        ls += (double)vx + (double)vy + (double)vz + (double)vw;
        lq += (double)vx * vx + (double)vy * vy + (double)vz * vz + (double)vw * vw;
    }
    __shared__ double sa[256], sb[256];
    sa[tid] = ls; sb[tid] = lq; __syncthreads();
    for (int s = 128; s > 0; s >>= 1) {
        if (tid < s) { sa[tid] += sa[tid + s]; sb[tid] += sb[tid + s]; }
        __syncthreads();
    }
    if (tid == 0) {
        const size_t pl = ((size_t)cb * gridDim.x + b) * gridDim.y + nb;
        partials[2 * pl] = sa[0]; partials[2 * pl + 1] = sb[0];
    }
}

// L4: combined finalize (1 block). Emits stats4 = {alpha_lo, beta_lo,
// alpha_hi, beta_hi}: out = alpha*v_raw + beta == (v_final - m2) * rs2.
__global__ __launch_bounds__(256) void k_fin_combined(const double* __restrict__ partials1,
                                                      int P1,
                                                      const double* __restrict__ partials2,
                                                      int P2, int P2lo,
                                                      float* __restrict__ stats4) {
    __shared__ double red[6][256];
    const int t = threadIdx.x;
    double s1 = 0.0, q1 = 0.0, s2l = 0.0, q2l = 0.0, s2h = 0.0, q2h = 0.0;
    for (int i = t; i < P1; i += 256) { s1 += partials1[2 * i]; q1 += partials1[2 * i + 1]; }
    for (int i = t; i < P2; i += 256) {
        const double s = partials2[2 * i], q = partials2[2 * i + 1];
        if (i < P2lo) { s2l += s; q2l += q; } else { s2h += s; q2h += q; }
    }
    red[0][t] = s1; red[1][t] = q1; red[2][t] = s2l;
    red[3][t] = q2l; red[4][t] = s2h; red[5][t] = q2h;
    __syncthreads();
    for (int s = 128; s > 0; s >>= 1) {
        if (t < s) {
#pragma unroll
            for (int r = 0; r < 6; ++r) red[r][t] += red[r][t + s];
        }
        __syncthreads();
    }
    if (t == 0) {
        const double nelem1 = 8388608.0;      // 8*2048*512
        const double cnt2   = 50331648.0;     // 8*8192*768
        const double cnthi  = 33554432.0;     // 8*8192*512
        const double S1 = red[0][0], Q1 = red[1][0];
        const double m1 = S1 / nelem1;
        const double v1 = (Q1 - S1 * S1 / nelem1) / (nelem1 - 1.0);
        const double sd1 = sqrt(v1 > 0.0 ? v1 : 0.0);
        const float rs1f = (float)(1.0 / (sd1 + 1e-5));
        const float m1f = (float)m1;
        const double a1 = (double)rs1f;
        const double b1 = -(double)m1f * (double)rs1f;
        const double S2l = red[2][0], Q2l = red[3][0];
        const double S2h = red[4][0], Q2h = red[5][0];
        const double Sf = S2l + a1 * S2h + b1 * cnthi;
        const double Qf = Q2l + a1 * a1 * Q2h + 2.0 * a1 * b1 * S2h + b1 * b1 * cnthi;
        const double m2 = Sf / cnt2;
        const double v2 = (Qf - Sf * Sf / cnt2) / (cnt2 - 1.0);
        const double sd2 = sqrt(v2 > 0.0 ? v2 : 0.0);
        const double rs2 = 1.0 / (sd2 + 1e-5);
        stats4[0] = (float)rs2;                 // alpha_lo (c < 256)
        stats4[1] = (float)(-m2 * rs2);         // beta_lo
        stats4[2] = (float)(a1 * rs2);          // alpha_hi (c >= 256)
        stats4[3] = (float)((b1 - m2) * rs2);   // beta_hi
    }
}

// L5: level-2 write pass: grid (x=B, y=128 n-tiles, z=12 c-blocks). Gather raw
// inter rows, apply per-region affine, write TRANSPOSED via 64x64 LDS tile.
__global__ __launch_bounds__(256) void k_interp2_write(const float* __restrict__ pts,
                                                       const float* __restrict__ cand_d,
                                                       const int* __restrict__ cand_i,
                                                       const float* __restrict__ stats4,
                                                       float* __restrict__ out) {
    __shared__ float tile[64][65];
    __shared__ int   si[64][3];
    __shared__ float sw[64][3];
    const int b = blockIdx.x, nt = blockIdx.y, cc = blockIdx.z;
    const float alpha = (cc < 4) ? stats4[0] : stats4[2];
    const float beta  = (cc < 4) ? stats4[1] : stats4[3];
    const int n0 = nt * 64, c0 = cc * 64;
    const int tid = threadIdx.x;
    if (tid < 64) {
        const size_t pt = (size_t)b * 8192 + n0 + tid;
        dev_merge6(cand_d + pt * 6, cand_i + pt * 6,
                   si[tid][0], si[tid][1], si[tid][2],
                   sw[tid][0], sw[tid][1], sw[tid][2]);
    }
    __syncthreads();
    const float* pb = pts + (size_t)b * 2048 * 768 + c0;
    const int cl = tid & 63;
    const int pg = tid >> 6;
#pragma unroll
    for (int pass = 0; pass < 16; ++pass) {
        const int nl = pass * 4 + pg;
        const float v = (sw[nl][0] * pb[(size_t)si[nl][0] * 768 + cl]
                       + sw[nl][1] * pb[(size_t)si[nl][1] * 768 + cl])
                       + sw[nl][2] * pb[(size_t)si[nl][2] * 768 + cl];
        tile[nl][cl] = alpha * v + beta;
    }
    __syncthreads();
    float* ob = out + (size_t)b * 896 * 8192 + (size_t)(128 + c0) * 8192 + n0;
    const int tn = tid & 63, tc0 = tid >> 6;
#pragma unroll
    for (int pass = 0; pass < 16; ++pass) {
        const int tc = pass * 4 + tc0;
        ob[(size_t)tc * 8192 + tn] = tile[tn][tc];
    }
}

extern "C" void kernel_launch(void* const* d_in, const int* in_sizes, int n_in,
                              void* d_out, int out_size, void* d_ws, size_t ws_size,
                              hipStream_t stream) {
    const float* xyz0 = (const float*)d_in[0];
    const float* xyz1 = (const float*)d_in[1];
    const float* xyz2 = (const float*)d_in[2];
    const float* x0   = (const float*)d_in[3];
    const float* x1   = (const float*)d_in[4];
    const float* x2   = (const float*)d_in[5];
    float* out = (float*)d_out;
    char* ws = (char*)d_ws;

    size_t off = 0;
    auto alloc = [&](size_t bytes) {
        size_t o = off;
        off = (off + bytes + 255) & ~(size_t)255;
        return o;
    };
    float*  stats4    = (float*)(ws + alloc(4 * sizeof(float)));
    double* partials1 = (double*)(ws + alloc((size_t)1024 * 2 * sizeof(double)));
    double* partials2 = (double*)(ws + alloc((size_t)6144 * 2 * sizeof(double)));
    float*  pts1      = (float*)(ws + alloc((size_t)8 * 512 * 512 * 4));   // x2^T
    float*  inter     = (float*)(ws + alloc((size_t)8 * 2048 * 768 * 4));  // RAW [8,2048,768]
    float*  cand_d2   = (float*)(ws + alloc((size_t)65536 * 6 * 4));
    int*    cand_i2   = (int*)(ws + alloc((size_t)65536 * 6 * 4));
    float*  cand_d1   = (float*)(ws + alloc((size_t)16384 * 6 * 4));
    int*    cand_i1   = (int*)(ws + alloc((size_t)16384 * 6 * 4));

    // L1: knn2 | knn1 | copy0 | transB | transA
    k_front<<<14976, 256, 0, stream>>>(xyz0, xyz1, xyz2, x0, x1, x2,
                                       pts1, inter, out,
                                       cand_d2, cand_i2, cand_d1, cand_i1);
    // L2: level-1 fused raw write + partials1
    k_interp1_fused<<<dim3(8, 128), 256, 0, stream>>>(
        pts1, cand_d1, cand_i1, inter, partials1);
    // L3: level-2 raw stats -> partials2 (cb-major: first 2048 = c<256)
    k_interp_stats<<<dim3(8, 256, 3), 256, 0, stream>>>(
        inter, cand_d2, cand_i2, 8192, 2048, 768, partials2);
    // L4: combined finalize -> stats4
    k_fin_combined<<<1, 256, 0, stream>>>(partials1, 1024, partials2, 6144, 2048, stats4);
    // L5: level-2 write with per-region affine
    k_interp2_write<<<dim3(8, 128, 12), 256, 0, stream>>>(inter, cand_d2, cand_i2,
                                                          stats4, out);
}

// Round 13
// 180.852 us; speedup vs baseline: 1.1871x; 1.0411x over previous
//
#include <hip/hip_runtime.h>
#include <cstdint>
#include <math.h>

// ---------------------------------------------------------------------------
// Problem constants
//   B=8
//   level 1: fine xyz1 [8,2048,3], coarse xyz2 [8,512,3], x1 [8,256,2048], x2 [8,512,512]
//   level 2: fine xyz0 [8,8192,3], coarse xyz1 [8,2048,3], x0 [8,128,8192]
//   out [8, 896, 8192] f32
// 5-launch schedule (inter holds RAW level-1 interp; normalization deferred
// into write2 as a per-region affine alpha*v+beta):
//   L1 k_front         : knn2 | knn1 | copy0 | transB | transA
//   L2 k_interp1_fused : gather pts1 -> raw inter[:, :, 256:768] + partials1
//   L3 k_interp_stats  : gather raw inter -> partials2 (per-cb region split)
//   L4 k_fin_combined  : double reduce + affine correction -> {a,b}x{lo,hi}
//   L5 k_interp2_write : gather raw inter, out = a*v + b (per c-block a,b)
// Rules learned:
//   - no per-block agent-scope fences/atomics in hot kernels (R7)
//   - LDS-staged knn beats uniform VMEM scan at this occupancy (R9)
//   - knn scan needs >=2 waves/SIMD; 1 pt/thread, 512 blocks (R11)
//   - per-iteration __any branch kills ds_read pipelining; batch 8 distances
//     before one guard (R12: unroll alone was neutral -> branch boundary)
// ---------------------------------------------------------------------------

// Merge 6 candidates (2 chunks x sorted top-3, chunk-major => ascending index
// order within equal distances; strict < keeps the earlier candidate, matching
// top_k tie-breaking). Weights = normalized inverse distances.
__device__ __forceinline__ void dev_merge6(const float* __restrict__ cd,
                                           const int* __restrict__ ci,
                                           int& o0, int& o1, int& o2,
                                           float& w0, float& w1, float& w2) {
    float d0 = 1e30f, d1 = 1e30f, d2 = 1e30f;
    int j0 = 0, j1 = 0, j2 = 0;
#pragma unroll
    for (int k = 0; k < 6; ++k) {
        const float d = cd[k];
        const int s = ci[k];
        const bool lt0 = d < d0, lt1 = d < d1, lt2 = d < d2;
        d2 = lt1 ? d1 : (lt2 ? d : d2);
        j2 = lt1 ? j1 : (lt2 ? s : j2);
        d1 = lt0 ? d0 : (lt1 ? d : d1);
        j1 = lt0 ? j0 : (lt1 ? s : j1);
        d0 = lt0 ? d : d0;
        j0 = lt0 ? s : j0;
    }
    const float a = 1.0f / (d0 + 1e-8f);
    const float b = 1.0f / (d1 + 1e-8f);
    const float c = 1.0f / (d2 + 1e-8f);
    const float ws = (a + b) + c;
    o0 = j0; o1 = j1; o2 = j2;
    w0 = a / ws; w1 = b / ws; w2 = c / ws;
}

// kNN chunk scan, batch-8 branchless-read form. 1 point/thread, coarse chunk
// staged in LDS. Per batch: 8 independent ds_read_b128 + 8 distance comps are
// issued BEFORE any branch (reads pipeline, one batched lgkmcnt wait), then a
// 7-op fminf tree and ONE __any guard. On trigger, the 8 precomputed
// distances are inserted sequentially in increasing s order -> bit-identical
// selection, order, and tie-breaking vs the scalar loop.
// Distance form bit-matches reference: fmaf(-2,dot,psq+cw) == (psq+cw)-2*dot.
template <int CHUNK>
__device__ __forceinline__ void dev_knn_lds(const float* __restrict__ fine,
                                            const float* __restrict__ coarse,
                                            int N, int S, int nch,
                                            int b, int nb, int chunk, int tid,
                                            float4* __restrict__ lc,
                                            float* __restrict__ cand_d,
                                            int* __restrict__ cand_i) {
#pragma clang fp contract(off)
    const int s0 = chunk * CHUNK;
    const float* cb = coarse + ((size_t)b * S + s0) * 3;
    for (int s = tid; s < CHUNK; s += 256) {
        const float x = cb[3 * s], y = cb[3 * s + 1], z = cb[3 * s + 2];
        lc[s] = make_float4(x, y, z, (x * x + y * y) + z * z);
    }
    __syncthreads();
    const int n = nb * 256 + tid;
    const float* fp = fine + ((size_t)b * N + n) * 3;
    const float px = fp[0], py = fp[1], pz = fp[2];
    const float psq = (px * px + py * py) + pz * pz;
    float d0 = 1e30f, d1 = 1e30f, d2 = 1e30f;
    int i0 = 0, i1 = 0, i2 = 0;
    for (int s8 = 0; s8 < CHUNK; s8 += 8) {
        float dbat0, dbat1, dbat2, dbat3, dbat4, dbat5, dbat6, dbat7;
        {
            const float4 c0 = lc[s8 + 0];
            const float4 c1 = lc[s8 + 1];
            const float4 c2 = lc[s8 + 2];
            const float4 c3 = lc[s8 + 3];
            const float4 c4 = lc[s8 + 4];
            const float4 c5 = lc[s8 + 5];
            const float4 c6 = lc[s8 + 6];
            const float4 c7 = lc[s8 + 7];
            dbat0 = fmaf(-2.0f, (px * c0.x + py * c0.y) + pz * c0.z, psq + c0.w);
            dbat1 = fmaf(-2.0f, (px * c1.x + py * c1.y) + pz * c1.z, psq + c1.w);
            dbat2 = fmaf(-2.0f, (px * c2.x + py * c2.y) + pz * c2.z, psq + c2.w);
            dbat3 = fmaf(-2.0f, (px * c3.x + py * c3.y) + pz * c3.z, psq + c3.w);
            dbat4 = fmaf(-2.0f, (px * c4.x + py * c4.y) + pz * c4.z, psq + c4.w);
            dbat5 = fmaf(-2.0f, (px * c5.x + py * c5.y) + pz * c5.z, psq + c5.w);
            dbat6 = fmaf(-2.0f, (px * c6.x + py * c6.y) + pz * c6.z, psq + c6.w);
            dbat7 = fmaf(-2.0f, (px * c7.x + py * c7.y) + pz * c7.z, psq + c7.w);
        }
        const float m01 = fminf(dbat0, dbat1);
        const float m23 = fminf(dbat2, dbat3);
        const float m45 = fminf(dbat4, dbat5);
        const float m67 = fminf(dbat6, dbat7);
        const float m03 = fminf(m01, m23);
        const float m47 = fminf(m45, m67);
        const float dmin8 = fminf(m03, m47);
        if (__any(dmin8 < d2)) {
            const float db[8] = {dbat0, dbat1, dbat2, dbat3,
                                 dbat4, dbat5, dbat6, dbat7};
#pragma unroll
            for (int u = 0; u < 8; ++u) {
                const float d = db[u];
                const int s = s8 + u;
                const bool lt0 = d < d0, lt1 = d < d1, lt2 = d < d2;
                d2 = lt1 ? d1 : (lt2 ? d : d2);
                i2 = lt1 ? i1 : (lt2 ? s : i2);
                d1 = lt0 ? d0 : (lt1 ? d : d1);
                i1 = lt0 ? i0 : (lt1 ? s : i1);
                d0 = lt0 ? d : d0;
                i0 = lt0 ? s : i0;
            }
        }
    }
    const size_t p = (((size_t)b * N + n) * nch + chunk) * 3;
    cand_d[p] = d0; cand_d[p + 1] = d1; cand_d[p + 2] = d2;
    cand_i[p] = s0 + i0; cand_i[p + 1] = s0 + i1; cand_i[p + 2] = s0 + i2;
}

__device__ __forceinline__ void dev_transpose(const float* __restrict__ in,
                                              float* __restrict__ out,
                                              int C, long in_bs, long out_bs, int out_rs,
                                              int b, int rt, int ct, int tid,
                                              float* __restrict__ tile /*[32][33]*/) {
    const int r0 = rt * 32, c0 = ct * 32;
    const float* inb = in + (size_t)b * in_bs;
    float* outb = out + (size_t)b * out_bs;
    const int tx = tid & 31, ty = tid >> 5;   // 32 x 8
#pragma unroll
    for (int i = 0; i < 32; i += 8) {
        tile[(ty + i) * 33 + tx] = inb[(size_t)(r0 + ty + i) * C + (c0 + tx)];
    }
    __syncthreads();
#pragma unroll
    for (int i = 0; i < 32; i += 8) {
        outb[(size_t)(c0 + ty + i) * out_rs + (r0 + tx)] = tile[tx * 33 + (ty + i)];
    }
}

// L1: fused front. Blocks:
//   [0,512)        knn level 2 (CHUNK=1024, nch=2): b=id>>6, nb=id&31, chunk=(id>>5)&1
//   [512,640)      knn level 1 (CHUNK=256,  nch=2): t=id-512: b=t>>4, nb=t&7, chunk=(t>>3)&1
//   [640,8832)     copy0  x0 -> out[:,0:128,:]
//   [8832,12928)   transB x1 [8,256,2048] -> inter[b][c][r] (rs=768)
//   [12928,14976)  transA x2 [8,512,512]  -> pts1 (rs=512)
__global__ __launch_bounds__(256) void k_front(const float* __restrict__ xyz0,
                                               const float* __restrict__ xyz1,
                                               const float* __restrict__ xyz2,
                                               const float* __restrict__ x0,
                                               const float* __restrict__ x1,
                                               const float* __restrict__ x2,
                                               float* __restrict__ pts1,
                                               float* __restrict__ inter,
                                               float* __restrict__ out,
                                               float* __restrict__ cand_d2,
                                               int* __restrict__ cand_i2,
                                               float* __restrict__ cand_d1,
                                               int* __restrict__ cand_i1) {
    __shared__ __align__(16) char smem[16384];   // union: lc (16K) | tile (4.2K)
    const int id = blockIdx.x;
    const int tid = threadIdx.x;
    if (id < 512) {
        dev_knn_lds<1024>(xyz0, xyz1, 8192, 2048, 2,
                          id >> 6, id & 31, (id >> 5) & 1, tid,
                          (float4*)smem, cand_d2, cand_i2);
    } else if (id < 640) {
        const int t = id - 512;
        dev_knn_lds<256>(xyz1, xyz2, 2048, 512, 2,
                         t >> 4, t & 7, (t >> 3) & 1, tid,
                         (float4*)smem, cand_d1, cand_i1);
    } else if (id < 8832) {                      // copy0
        const size_t i = (size_t)(id - 640) * 256 + tid;
        const size_t b = i >> 18;
        const size_t off = i & (((size_t)1 << 18) - 1);
        const float4* src = (const float4*)(x0 + b * (size_t)128 * 8192);
        float4* dst = (float4*)(out + b * (size_t)896 * 8192);
        dst[off] = src[off];
    } else if (id < 12928) {                     // transB
        const int t = id - 8832;
        const int ct = t & 63, rt = (t >> 6) & 7, b = t >> 9;
        dev_transpose(x1, inter, 2048, 256 * 2048, (long)2048 * 768, 768,
                      b, rt, ct, tid, (float*)smem);
    } else {                                     // transA
        const int t = id - 12928;
        const int ct = t & 15, rt = (t >> 4) & 15, b = t >> 8;
        dev_transpose(x2, pts1, 512, 512 * 512, 512 * 512, 512,
                      b, rt, ct, tid, (float*)smem);
    }
}

// L2: level-1 fused gather: write RAW interp to inter[:, :, 256:768] and
// accumulate double partials. Grid (x=8, y=128); 16 points/block.
__global__ __launch_bounds__(256) void k_interp1_fused(const float* __restrict__ pts,
                                                       const float* __restrict__ cand_d,
                                                       const int* __restrict__ cand_i,
                                                       float* __restrict__ inter,
                                                       double* __restrict__ partials1) {
    __shared__ int   si[16][3];
    __shared__ float sw[16][3];
    const int b = blockIdx.x, nb = blockIdx.y;
    const int n0 = nb * 16;
    const int tid = threadIdx.x;
    if (tid < 16) {
        const size_t pt = (size_t)b * 2048 + n0 + tid;
        dev_merge6(cand_d + pt * 6, cand_i + pt * 6,
                   si[tid][0], si[tid][1], si[tid][2],
                   sw[tid][0], sw[tid][1], sw[tid][2]);
    }
    __syncthreads();
    const float4* pb4 = (const float4*)(pts + (size_t)b * 512 * 512);
    const int pg = tid >> 6, f = tid & 63;
    double ls = 0.0, lq = 0.0;
#pragma unroll
    for (int g = 0; g < 4; ++g) {
        const int pl = g * 4 + pg;
        const size_t p = (size_t)b * 2048 + n0 + pl;
        const size_t r0 = (size_t)si[pl][0] * 128;
        const size_t r1 = (size_t)si[pl][1] * 128;
        const size_t r2 = (size_t)si[pl][2] * 128;
        const float w0 = sw[pl][0], w1 = sw[pl][1], w2 = sw[pl][2];
        float4* out4 = (float4*)(inter + p * 768 + 256);
#pragma unroll
        for (int k = 0; k < 2; ++k) {
            const int c = f + k * 64;
            const float4 a = pb4[r0 + c], d = pb4[r1 + c], e = pb4[r2 + c];
            float4 v;
            v.x = (w0 * a.x + w1 * d.x) + w2 * e.x;
            v.y = (w0 * a.y + w1 * d.y) + w2 * e.y;
            v.z = (w0 * a.z + w1 * d.z) + w2 * e.z;
            v.w = (w0 * a.w + w1 * d.w) + w2 * e.w;
            out4[c] = v;
            ls += (double)v.x + (double)v.y + (double)v.z + (double)v.w;
            lq += (double)v.x * v.x + (double)v.y * v.y
                + (double)v.z * v.z + (double)v.w * v.w;
        }
    }
    __shared__ double sa[256], sb[256];
    sa[tid] = ls; sb[tid] = lq; __syncthreads();
    for (int s = 128; s > 0; s >>= 1) {
        if (tid < s) { sa[tid] += sa[tid + s]; sb[tid] += sb[tid + s]; }
        __syncthreads();
    }
    if (tid == 0) {
        const size_t pl = (size_t)b * gridDim.y + nb;
        partials1[2 * pl] = sa[0]; partials1[2 * pl + 1] = sb[0];
    }
}

// L3: stats gather over raw inter; per-block double partials, cb-major layout
// so the finalize can split c<256 (cb=0) from c>=256 (cb=1,2).
// Grid (x=B, y=N/32, z=C/256); blockIdx.x = batch -> XCD-pinned L2 reuse.
__global__ __launch_bounds__(256) void k_interp_stats(const float* __restrict__ pts,
                                                      const float* __restrict__ cand_d,
                                                      const int* __restrict__ cand_i,
                                                      int N, int S, int C,
                                                      double* __restrict__ partials) {
    __shared__ int   si[32][3];
    __shared__ float sw[32][3];
    const int b = blockIdx.x, nb = blockIdx.y, cb = blockIdx.z;
    const int n0 = nb * 32;
    const int tid = threadIdx.x;
    if (tid < 32) {
        const size_t pt = (size_t)b * N + n0 + tid;
        dev_merge6(cand_d + pt * 6, cand_i + pt * 6,
                   si[tid][0], si[tid][1], si[tid][2],
                   sw[tid][0], sw[tid][1], sw[tid][2]);
    }
    __syncthreads();
    const int C4 = C >> 2;
    const float4* pbf = (const float4*)(pts + (size_t)b * S * C) + (cb * 64);
    const int f = tid & 63;
    const int pg = tid >> 6;
    double ls = 0.0, lq = 0.0;
#pragma unroll
    for (int g = 0; g < 8; ++g) {
        const int nl = g * 4 + pg;
        const size_t r0 = (size_t)si[nl][0] * C4;
        const size_t r1 = (size_t)si[nl][1] * C4;
        const size_t r2 = (size_t)si[nl][2] * C4;
        const float w0 = sw[nl][0], w1 = sw[nl][1], w2 = sw[nl][2];
        const float4 a = pbf[r0 + f], c = pbf[r1 + f], e = pbf[r2 + f];
        const float vx = (w0 * a.x + w1 * c.x) + w2 * e.x;
        const float vy = (w0 * a.y + w1 * c.y) + w2 * e.y;
        const float vz = (w0 * a.z + w1 * c.z) + w2 * e.z;
        const float vw = (w0 * a.w + w1 * c.w) + w2 * e.w;
        ls += (double)vx + (double)vy + (double)vz + (double)vw;
        lq += (double)vx * vx + (double)vy * vy + (double)vz * vz + (double)vw * vw;
    }
    __shared__ double sa[256], sb[256];
    sa[tid] = ls; sb[tid] = lq; __syncthreads();
    for (int s = 128; s > 0; s >>= 1) {
        if (tid < s) { sa[tid] += sa[tid + s]; sb[tid] += sb[tid + s]; }
        __syncthreads();
    }
    if (tid == 0) {
        const size_t pl = ((size_t)cb * gridDim.x + b) * gridDim.y + nb;
        partials[2 * pl] = sa[0]; partials[2 * pl + 1] = sb[0];
    }
}

// L4: combined finalize (1 block). Emits stats4 = {alpha_lo, beta_lo,
// alpha_hi, beta_hi}: out = alpha*v_raw + beta == (v_final - m2) * rs2.
__global__ __launch_bounds__(256) void k_fin_combined(const double* __restrict__ partials1,
                                                      int P1,
                                                      const double* __restrict__ partials2,
                                                      int P2, int P2lo,
                                                      float* __restrict__ stats4) {
    __shared__ double red[6][256];
    const int t = threadIdx.x;
    double s1 = 0.0, q1 = 0.0, s2l = 0.0, q2l = 0.0, s2h = 0.0, q2h = 0.0;
    for (int i = t; i < P1; i += 256) { s1 += partials1[2 * i]; q1 += partials1[2 * i + 1]; }
    for (int i = t; i < P2; i += 256) {
        const double s = partials2[2 * i], q = partials2[2 * i + 1];
        if (i < P2lo) { s2l += s; q2l += q; } else { s2h += s; q2h += q; }
    }
    red[0][t] = s1; red[1][t] = q1; red[2][t] = s2l;
    red[3][t] = q2l; red[4][t] = s2h; red[5][t] = q2h;
    __syncthreads();
    for (int s = 128; s > 0; s >>= 1) {
        if (t < s) {
#pragma unroll
            for (int r = 0; r < 6; ++r) red[r][t] += red[r][t + s];
        }
        __syncthreads();
    }
    if (t == 0) {
        const double nelem1 = 8388608.0;      // 8*2048*512
        const double cnt2   = 50331648.0;     // 8*8192*768
        const double cnthi  = 33554432.0;     // 8*8192*512
        const double S1 = red[0][0], Q1 = red[1][0];
        const double m1 = S1 / nelem1;
        const double v1 = (Q1 - S1 * S1 / nelem1) / (nelem1 - 1.0);
        const double sd1 = sqrt(v1 > 0.0 ? v1 : 0.0);
        const float rs1f = (float)(1.0 / (sd1 + 1e-5));
        const float m1f = (float)m1;
        const double a1 = (double)rs1f;
        const double b1 = -(double)m1f * (double)rs1f;
        const double S2l = red[2][0], Q2l = red[3][0];
        const double S2h = red[4][0], Q2h = red[5][0];
        const double Sf = S2l + a1 * S2h + b1 * cnthi;
        const double Qf = Q2l + a1 * a1 * Q2h + 2.0 * a1 * b1 * S2h + b1 * b1 * cnthi;
        const double m2 = Sf / cnt2;
        const double v2 = (Qf - Sf * Sf / cnt2) / (cnt2 - 1.0);
        const double sd2 = sqrt(v2 > 0.0 ? v2 : 0.0);
        const double rs2 = 1.0 / (sd2 + 1e-5);
        stats4[0] = (float)rs2;                 // alpha_lo (c < 256)
        stats4[1] = (float)(-m2 * rs2);         // beta_lo
        stats4[2] = (float)(a1 * rs2);          // alpha_hi (c >= 256)
        stats4[3] = (float)((b1 - m2) * rs2);   // beta_hi
    }
}

// L5: level-2 write pass: grid (x=B, y=128 n-tiles, z=12 c-blocks). Gather raw
// inter rows, apply per-region affine, write TRANSPOSED via 64x64 LDS tile.
__global__ __launch_bounds__(256) void k_interp2_write(const float* __restrict__ pts,
                                                       const float* __restrict__ cand_d,
                                                       const int* __restrict__ cand_i,
                                                       const float* __restrict__ stats4,
                                                       float* __restrict__ out) {
    __shared__ float tile[64][65];
    __shared__ int   si[64][3];
    __shared__ float sw[64][3];
    const int b = blockIdx.x, nt = blockIdx.y, cc = blockIdx.z;
    const float alpha = (cc < 4) ? stats4[0] : stats4[2];
    const float beta  = (cc < 4) ? stats4[1] : stats4[3];
    const int n0 = nt * 64, c0 = cc * 64;
    const int tid = threadIdx.x;
    if (tid < 64) {
        const size_t pt = (size_t)b * 8192 + n0 + tid;
        dev_merge6(cand_d + pt * 6, cand_i + pt * 6,
                   si[tid][0], si[tid][1], si[tid][2],
                   sw[tid][0], sw[tid][1], sw[tid][2]);
    }
    __syncthreads();
    const float* pb = pts + (size_t)b * 2048 * 768 + c0;
    const int cl = tid & 63;
    const int pg = tid >> 6;
#pragma unroll
    for (int pass = 0; pass < 16; ++pass) {
        const int nl = pass * 4 + pg;
        const float v = (sw[nl][0] * pb[(size_t)si[nl][0] * 768 + cl]
                       + sw[nl][1] * pb[(size_t)si[nl][1] * 768 + cl])
                       + sw[nl][2] * pb[(size_t)si[nl][2] * 768 + cl];
        tile[nl][cl] = alpha * v + beta;
    }
    __syncthreads();
    float* ob = out + (size_t)b * 896 * 8192 + (size_t)(128 + c0) * 8192 + n0;
    const int tn = tid & 63, tc0 = tid >> 6;
#pragma unroll
    for (int pass = 0; pass < 16; ++pass) {
        const int tc = pass * 4 + tc0;
        ob[(size_t)tc * 8192 + tn] = tile[tn][tc];
    }
}

extern "C" void kernel_launch(void* const* d_in, const int* in_sizes, int n_in,
                              void* d_out, int out_size, void* d_ws, size_t ws_size,
                              hipStream_t stream) {
    const float* xyz0 = (const float*)d_in[0];
    const float* xyz1 = (const float*)d_in[1];
    const float* xyz2 = (const float*)d_in[2];
    const float* x0   = (const float*)d_in[3];
    const float* x1   = (const float*)d_in[4];
    const float* x2   = (const float*)d_in[5];
    float* out = (float*)d_out;
    char* ws = (char*)d_ws;

    size_t off = 0;
    auto alloc = [&](size_t bytes) {
        size_t o = off;
        off = (off + bytes + 255) & ~(size_t)255;
        return o;
    };
    float*  stats4    = (float*)(ws + alloc(4 * sizeof(float)));
    double* partials1 = (double*)(ws + alloc((size_t)1024 * 2 * sizeof(double)));
    double* partials2 = (double*)(ws + alloc((size_t)6144 * 2 * sizeof(double)));
    float*  pts1      = (float*)(ws + alloc((size_t)8 * 512 * 512 * 4));   // x2^T
    float*  inter     = (float*)(ws + alloc((size_t)8 * 2048 * 768 * 4));  // RAW [8,2048,768]
    float*  cand_d2   = (float*)(ws + alloc((size_t)65536 * 6 * 4));
    int*    cand_i2   = (int*)(ws + alloc((size_t)65536 * 6 * 4));
    float*  cand_d1   = (float*)(ws + alloc((size_t)16384 * 6 * 4));
    int*    cand_i1   = (int*)(ws + alloc((size_t)16384 * 6 * 4));

    // L1: knn2 | knn1 | copy0 | transB | transA
    k_front<<<14976, 256, 0, stream>>>(xyz0, xyz1, xyz2, x0, x1, x2,
                                       pts1, inter, out,
                                       cand_d2, cand_i2, cand_d1, cand_i1);
    // L2: level-1 fused raw write + partials1
    k_interp1_fused<<<dim3(8, 128), 256, 0, stream>>>(
        pts1, cand_d1, cand_i1, inter, partials1);
    // L3: level-2 raw stats -> partials2 (cb-major: first 2048 = c<256)
    k_interp_stats<<<dim3(8, 256, 3), 256, 0, stream>>>(
        inter, cand_d2, cand_i2, 8192, 2048, 768, partials2);
    // L4: combined finalize -> stats4
    k_fin_combined<<<1, 256, 0, stream>>>(partials1, 1024, partials2, 6144, 2048, stats4);
    // L5: level-2 write with per-region affine
    k_interp2_write<<<dim3(8, 128, 12), 256, 0, stream>>>(inter, cand_d2, cand_i2,
                                                          stats4, out);
}

// Round 14
// 177.401 us; speedup vs baseline: 1.2102x; 1.0195x over previous
//
#include <hip/hip_runtime.h>
#include <cstdint>
#include <math.h>

// ---------------------------------------------------------------------------
// Problem constants
//   B=8
//   level 1: fine xyz1 [8,2048,3], coarse xyz2 [8,512,3], x1 [8,256,2048], x2 [8,512,512]
//   level 2: fine xyz0 [8,8192,3], coarse xyz1 [8,2048,3], x0 [8,128,8192]
//   out [8, 896, 8192] f32
// 5-launch schedule (inter holds RAW level-1 interp; normalization deferred
// into write2 as a per-region affine alpha*v+beta):
//   L1 k_front         : knn2 | knn1 | copy0 | transB | transA
//   L2 k_interp1_fused : gather pts1 -> raw inter[:, :, 256:768] + partials1
//   L3 k_interp_stats  : gather raw inter -> partials2 (per-cb region split)
//   L4 k_fin_combined  : double reduce + affine correction -> {a,b}x{lo,hi}
//   L5 k_interp2_write : gather raw inter, out = a*v + b (per c-block a,b)
// Rules learned:
//   - no per-block agent-scope fences/atomics in hot kernels (R7)
//   - LDS-staged knn beats uniform VMEM scan at this occupancy (R9)
//   - knn scan needs >=2 waves/SIMD (512 blocks) (R11)
//   - LDS issue count is the knn floor; batching doesn't cut it (R13) ->
//     2 fine points per LDS read (same 512 blocks via nch=4), branchless
//     (the __any guard never skips at 64-lane granularity; deleting it lets
//      reads pipeline across batches)
// ---------------------------------------------------------------------------

// Merge NC candidates (NC/3 chunks x sorted top-3, chunk-major => ascending
// index order within equal distances; strict < keeps the earlier candidate,
// matching top_k tie-breaking). Weights = normalized inverse distances.
template <int NC>
__device__ __forceinline__ void dev_merge(const float* __restrict__ cd,
                                          const int* __restrict__ ci,
                                          int& o0, int& o1, int& o2,
                                          float& w0, float& w1, float& w2) {
    float d0 = 1e30f, d1 = 1e30f, d2 = 1e30f;
    int j0 = 0, j1 = 0, j2 = 0;
#pragma unroll
    for (int k = 0; k < NC; ++k) {
        const float d = cd[k];
        const int s = ci[k];
        const bool lt0 = d < d0, lt1 = d < d1, lt2 = d < d2;
        d2 = lt1 ? d1 : (lt2 ? d : d2);
        j2 = lt1 ? j1 : (lt2 ? s : j2);
        d1 = lt0 ? d0 : (lt1 ? d : d1);
        j1 = lt0 ? j0 : (lt1 ? s : j1);
        d0 = lt0 ? d : d0;
        j0 = lt0 ? s : j0;
    }
    const float a = 1.0f / (d0 + 1e-8f);
    const float b = 1.0f / (d1 + 1e-8f);
    const float c = 1.0f / (d2 + 1e-8f);
    const float ws = (a + b) + c;
    o0 = j0; o1 = j1; o2 = j2;
    w0 = a / ws; w1 = b / ws; w2 = c / ws;
}

// Branchless sorted-top3 insert (bit-identical to sequential scan insert).
__device__ __forceinline__ void dev_ins3(float d, int s,
                                         float& d0, float& d1, float& d2,
                                         int& i0, int& i1, int& i2) {
    const bool lt0 = d < d0, lt1 = d < d1, lt2 = d < d2;
    d2 = lt1 ? d1 : (lt2 ? d : d2);
    i2 = lt1 ? i1 : (lt2 ? s : i2);
    d1 = lt0 ? d0 : (lt1 ? d : d1);
    i1 = lt0 ? i0 : (lt1 ? s : i1);
    d0 = lt0 ? d : d0;
    i0 = lt0 ? s : i0;
}

// kNN scan, 2 fine points per thread, batch-8, fully branchless.
// Coarse chunk staged in LDS; each ds_read_b128 feeds BOTH points' distance
// computations (halves the LDS-pipe issue count, the R13-identified floor).
// Block covers 512 fine points: A = n0+tid, B = n0+256+tid.
// Distance form bit-matches reference: fmaf(-2,dot,psq+cw) == (psq+cw)-2*dot.
template <int CHUNK>
__device__ __forceinline__ void dev_knn2pt(const float* __restrict__ fine,
                                           const float* __restrict__ coarse,
                                           int N, int S, int nch,
                                           int b, int nb, int chunk, int tid,
                                           float4* __restrict__ lc,
                                           float* __restrict__ cand_d,
                                           int* __restrict__ cand_i) {
#pragma clang fp contract(off)
    const int s0 = chunk * CHUNK;
    const float* cb = coarse + ((size_t)b * S + s0) * 3;
    for (int s = tid; s < CHUNK; s += 256) {
        const float x = cb[3 * s], y = cb[3 * s + 1], z = cb[3 * s + 2];
        lc[s] = make_float4(x, y, z, (x * x + y * y) + z * z);
    }
    __syncthreads();
    const int na = nb * 512 + tid;
    const int nB = na + 256;
    const float* fa = fine + ((size_t)b * N + na) * 3;
    const float* fb = fine + ((size_t)b * N + nB) * 3;
    const float ax = fa[0], ay = fa[1], az = fa[2];
    const float bx = fb[0], by = fb[1], bz = fb[2];
    const float asq = (ax * ax + ay * ay) + az * az;
    const float bsq = (bx * bx + by * by) + bz * bz;
    float da0 = 1e30f, da1 = 1e30f, da2 = 1e30f;
    float db0 = 1e30f, db1 = 1e30f, db2 = 1e30f;
    int ia0 = 0, ia1 = 0, ia2 = 0;
    int ib0 = 0, ib1 = 0, ib2 = 0;
    for (int s8 = 0; s8 < CHUNK; s8 += 8) {
        float dA[8], dB[8];
#pragma unroll
        for (int u = 0; u < 8; ++u) {
            const float4 c = lc[s8 + u];
            dA[u] = fmaf(-2.0f, (ax * c.x + ay * c.y) + az * c.z, asq + c.w);
            dB[u] = fmaf(-2.0f, (bx * c.x + by * c.y) + bz * c.z, bsq + c.w);
        }
#pragma unroll
        for (int u = 0; u < 8; ++u) {
            dev_ins3(dA[u], s8 + u, da0, da1, da2, ia0, ia1, ia2);
            dev_ins3(dB[u], s8 + u, db0, db1, db2, ib0, ib1, ib2);
        }
    }
    const size_t pa = (((size_t)b * N + na) * nch + chunk) * 3;
    cand_d[pa] = da0; cand_d[pa + 1] = da1; cand_d[pa + 2] = da2;
    cand_i[pa] = s0 + ia0; cand_i[pa + 1] = s0 + ia1; cand_i[pa + 2] = s0 + ia2;
    const size_t pb = (((size_t)b * N + nB) * nch + chunk) * 3;
    cand_d[pb] = db0; cand_d[pb + 1] = db1; cand_d[pb + 2] = db2;
    cand_i[pb] = s0 + ib0; cand_i[pb + 1] = s0 + ib1; cand_i[pb + 2] = s0 + ib2;
}

// 1-pt/thread batch-8 branchless scan (level 1 -- scan work is trivial).
template <int CHUNK>
__device__ __forceinline__ void dev_knn1pt(const float* __restrict__ fine,
                                           const float* __restrict__ coarse,
                                           int N, int S, int nch,
                                           int b, int nb, int chunk, int tid,
                                           float4* __restrict__ lc,
                                           float* __restrict__ cand_d,
                                           int* __restrict__ cand_i) {
#pragma clang fp contract(off)
    const int s0 = chunk * CHUNK;
    const float* cb = coarse + ((size_t)b * S + s0) * 3;
    for (int s = tid; s < CHUNK; s += 256) {
        const float x = cb[3 * s], y = cb[3 * s + 1], z = cb[3 * s + 2];
        lc[s] = make_float4(x, y, z, (x * x + y * y) + z * z);
    }
    __syncthreads();
    const int n = nb * 256 + tid;
    const float* fp = fine + ((size_t)b * N + n) * 3;
    const float px = fp[0], py = fp[1], pz = fp[2];
    const float psq = (px * px + py * py) + pz * pz;
    float d0 = 1e30f, d1 = 1e30f, d2 = 1e30f;
    int i0 = 0, i1 = 0, i2 = 0;
    for (int s8 = 0; s8 < CHUNK; s8 += 8) {
        float dv[8];
#pragma unroll
        for (int u = 0; u < 8; ++u) {
            const float4 c = lc[s8 + u];
            dv[u] = fmaf(-2.0f, (px * c.x + py * c.y) + pz * c.z, psq + c.w);
        }
#pragma unroll
        for (int u = 0; u < 8; ++u) {
            dev_ins3(dv[u], s8 + u, d0, d1, d2, i0, i1, i2);
        }
    }
    const size_t p = (((size_t)b * N + n) * nch + chunk) * 3;
    cand_d[p] = d0; cand_d[p + 1] = d1; cand_d[p + 2] = d2;
    cand_i[p] = s0 + i0; cand_i[p + 1] = s0 + i1; cand_i[p + 2] = s0 + i2;
}

__device__ __forceinline__ void dev_transpose(const float* __restrict__ in,
                                              float* __restrict__ out,
                                              int C, long in_bs, long out_bs, int out_rs,
                                              int b, int rt, int ct, int tid,
                                              float* __restrict__ tile /*[32][33]*/) {
    const int r0 = rt * 32, c0 = ct * 32;
    const float* inb = in + (size_t)b * in_bs;
    float* outb = out + (size_t)b * out_bs;
    const int tx = tid & 31, ty = tid >> 5;   // 32 x 8
#pragma unroll
    for (int i = 0; i < 32; i += 8) {
        tile[(ty + i) * 33 + tx] = inb[(size_t)(r0 + ty + i) * C + (c0 + tx)];
    }
    __syncthreads();
#pragma unroll
    for (int i = 0; i < 32; i += 8) {
        outb[(size_t)(c0 + ty + i) * out_rs + (r0 + tx)] = tile[tx * 33 + (ty + i)];
    }
}

// L1: fused front. Blocks:
//   [0,512)        knn level 2, 2pt/thread (CHUNK=512, nch=4, 512 pts/block):
//                  b=id>>6, nb=id&15, chunk=(id>>4)&3
//   [512,640)      knn level 1, 1pt/thread (CHUNK=256, nch=2):
//                  t=id-512: b=t>>4, nb=t&7, chunk=(t>>3)&1
//   [640,8832)     copy0  x0 -> out[:,0:128,:]
//   [8832,12928)   transB x1 [8,256,2048] -> inter[b][c][r] (rs=768)
//   [12928,14976)  transA x2 [8,512,512]  -> pts1 (rs=512)
__global__ __launch_bounds__(256) void k_front(const float* __restrict__ xyz0,
                                               const float* __restrict__ xyz1,
                                               const float* __restrict__ xyz2,
                                               const float* __restrict__ x0,
                                               const float* __restrict__ x1,
                                               const float* __restrict__ x2,
                                               float* __restrict__ pts1,
                                               float* __restrict__ inter,
                                               float* __restrict__ out,
                                               float* __restrict__ cand_d2,
                                               int* __restrict__ cand_i2,
                                               float* __restrict__ cand_d1,
                                               int* __restrict__ cand_i1) {
    __shared__ __align__(16) char smem[8192];    // union: lc (8K) | tile (4.2K)
    const int id = blockIdx.x;
    const int tid = threadIdx.x;
    if (id < 512) {
        dev_knn2pt<512>(xyz0, xyz1, 8192, 2048, 4,
                        id >> 6, id & 15, (id >> 4) & 3, tid,
                        (float4*)smem, cand_d2, cand_i2);
    } else if (id < 640) {
        const int t = id - 512;
        dev_knn1pt<256>(xyz1, xyz2, 2048, 512, 2,
                        t >> 4, t & 7, (t >> 3) & 1, tid,
                        (float4*)smem, cand_d1, cand_i1);
    } else if (id < 8832) {                      // copy0
        const size_t i = (size_t)(id - 640) * 256 + tid;
        const size_t b = i >> 18;
        const size_t off = i & (((size_t)1 << 18) - 1);
        const float4* src = (const float4*)(x0 + b * (size_t)128 * 8192);
        float4* dst = (float4*)(out + b * (size_t)896 * 8192);
        dst[off] = src[off];
    } else if (id < 12928) {                     // transB
        const int t = id - 8832;
        const int ct = t & 63, rt = (t >> 6) & 7, b = t >> 9;
        dev_transpose(x1, inter, 2048, 256 * 2048, (long)2048 * 768, 768,
                      b, rt, ct, tid, (float*)smem);
    } else {                                     // transA
        const int t = id - 12928;
        const int ct = t & 15, rt = (t >> 4) & 15, b = t >> 8;
        dev_transpose(x2, pts1, 512, 512 * 512, 512 * 512, 512,
                      b, rt, ct, tid, (float*)smem);
    }
}

// L2: level-1 fused gather: write RAW interp to inter[:, :, 256:768] and
// accumulate double partials. Grid (x=8, y=128); 16 points/block.
__global__ __launch_bounds__(256) void k_interp1_fused(const float* __restrict__ pts,
                                                       const float* __restrict__ cand_d,
                                                       const int* __restrict__ cand_i,
                                                       float* __restrict__ inter,
                                                       double* __restrict__ partials1) {
    __shared__ int   si[16][3];
    __shared__ float sw[16][3];
    const int b = blockIdx.x, nb = blockIdx.y;
    const int n0 = nb * 16;
    const int tid = threadIdx.x;
    if (tid < 16) {
        const size_t pt = (size_t)b * 2048 + n0 + tid;
        dev_merge<6>(cand_d + pt * 6, cand_i + pt * 6,
                     si[tid][0], si[tid][1], si[tid][2],
                     sw[tid][0], sw[tid][1], sw[tid][2]);
    }
    __syncthreads();
    const float4* pb4 = (const float4*)(pts + (size_t)b * 512 * 512);
    const int pg = tid >> 6, f = tid & 63;
    double ls = 0.0, lq = 0.0;
#pragma unroll
    for (int g = 0; g < 4; ++g) {
        const int pl = g * 4 + pg;
        const size_t p = (size_t)b * 2048 + n0 + pl;
        const size_t r0 = (size_t)si[pl][0] * 128;
        const size_t r1 = (size_t)si[pl][1] * 128;
        const size_t r2 = (size_t)si[pl][2] * 128;
        const float w0 = sw[pl][0], w1 = sw[pl][1], w2 = sw[pl][2];
        float4* out4 = (float4*)(inter + p * 768 + 256);
#pragma unroll
        for (int k = 0; k < 2; ++k) {
            const int c = f + k * 64;
            const float4 a = pb4[r0 + c], d = pb4[r1 + c], e = pb4[r2 + c];
            float4 v;
            v.x = (w0 * a.x + w1 * d.x) + w2 * e.x;
            v.y = (w0 * a.y + w1 * d.y) + w2 * e.y;
            v.z = (w0 * a.z + w1 * d.z) + w2 * e.z;
            v.w = (w0 * a.w + w1 * d.w) + w2 * e.w;
            out4[c] = v;
            ls += (double)v.x + (double)v.y + (double)v.z + (double)v.w;
            lq += (double)v.x * v.x + (double)v.y * v.y
                + (double)v.z * v.z + (double)v.w * v.w;
        }
    }
    __shared__ double sa[256], sb[256];
    sa[tid] = ls; sb[tid] = lq; __syncthreads();
    for (int s = 128; s > 0; s >>= 1) {
        if (tid < s) { sa[tid] += sa[tid + s]; sb[tid] += sb[tid + s]; }
        __syncthreads();
    }
    if (tid == 0) {
        const size_t pl = (size_t)b * gridDim.y + nb;
        partials1[2 * pl] = sa[0]; partials1[2 * pl + 1] = sb[0];
    }
}

// L3: stats gather over raw inter; per-block double partials, cb-major layout
// so the finalize can split c<256 (cb=0) from c>=256 (cb=1,2).
// Grid (x=B, y=N/32, z=C/256); blockIdx.x = batch -> XCD-pinned L2 reuse.
__global__ __launch_bounds__(256) void k_interp_stats(const float* __restrict__ pts,
                                                      const float* __restrict__ cand_d,
                                                      const int* __restrict__ cand_i,
                                                      int N, int S, int C,
                                                      double* __restrict__ partials) {
    __shared__ int   si[32][3];
    __shared__ float sw[32][3];
    const int b = blockIdx.x, nb = blockIdx.y, cb = blockIdx.z;
    const int n0 = nb * 32;
    const int tid = threadIdx.x;
    if (tid < 32) {
        const size_t pt = (size_t)b * N + n0 + tid;
        dev_merge<12>(cand_d + pt * 12, cand_i + pt * 12,
                      si[tid][0], si[tid][1], si[tid][2],
                      sw[tid][0], sw[tid][1], sw[tid][2]);
    }
    __syncthreads();
    const int C4 = C >> 2;
    const float4* pbf = (const float4*)(pts + (size_t)b * S * C) + (cb * 64);
    const int f = tid & 63;
    const int pg = tid >> 6;
    double ls = 0.0, lq = 0.0;
#pragma unroll
    for (int g = 0; g < 8; ++g) {
        const int nl = g * 4 + pg;
        const size_t r0 = (size_t)si[nl][0] * C4;
        const size_t r1 = (size_t)si[nl][1] * C4;
        const size_t r2 = (size_t)si[nl][2] * C4;
        const float w0 = sw[nl][0], w1 = sw[nl][1], w2 = sw[nl][2];
        const float4 a = pbf[r0 + f], c = pbf[r1 + f], e = pbf[r2 + f];
        const float vx = (w0 * a.x + w1 * c.x) + w2 * e.x;
        const float vy = (w0 * a.y + w1 * c.y) + w2 * e.y;
        const float vz = (w0 * a.z + w1 * c.z) + w2 * e.z;
        const float vw = (w0 * a.w + w1 * c.w) + w2 * e.w;
        ls += (double)vx + (double)vy + (double)vz + (double)vw;
        lq += (double)vx * vx + (double)vy * vy + (double)vz * vz + (double)vw * vw;
    }
    __shared__ double sa[256], sb[256];
    sa[tid] = ls; sb[tid] = lq; __syncthreads();
    for (int s = 128; s > 0; s >>= 1) {
        if (tid < s) { sa[tid] += sa[tid + s]; sb[tid] += sb[tid + s]; }
        __syncthreads();
    }
    if (tid == 0) {
        const size_t pl = ((size_t)cb * gridDim.x + b) * gridDim.y + nb;
        partials[2 * pl] = sa[0]; partials[2 * pl + 1] = sb[0];
    }
}

// L4: combined finalize (1 block). Emits stats4 = {alpha_lo, beta_lo,
// alpha_hi, beta_hi}: out = alpha*v_raw + beta == (v_final - m2) * rs2.
__global__ __launch_bounds__(256) void k_fin_combined(const double* __restrict__ partials1,
                                                      int P1,
                                                      const double* __restrict__ partials2,
                                                      int P2, int P2lo,
                                                      float* __restrict__ stats4) {
    __shared__ double red[6][256];
    const int t = threadIdx.x;
    double s1 = 0.0, q1 = 0.0, s2l = 0.0, q2l = 0.0, s2h = 0.0, q2h = 0.0;
    for (int i = t; i < P1; i += 256) { s1 += partials1[2 * i]; q1 += partials1[2 * i + 1]; }
    for (int i = t; i < P2; i += 256) {
        const double s = partials2[2 * i], q = partials2[2 * i + 1];
        if (i < P2lo) { s2l += s; q2l += q; } else { s2h += s; q2h += q; }
    }
    red[0][t] = s1; red[1][t] = q1; red[2][t] = s2l;
    red[3][t] = q2l; red[4][t] = s2h; red[5][t] = q2h;
    __syncthreads();
    for (int s = 128; s > 0; s >>= 1) {
        if (t < s) {
#pragma unroll
            for (int r = 0; r < 6; ++r) red[r][t] += red[r][t + s];
        }
        __syncthreads();
    }
    if (t == 0) {
        const double nelem1 = 8388608.0;      // 8*2048*512
        const double cnt2   = 50331648.0;     // 8*8192*768
        const double cnthi  = 33554432.0;     // 8*8192*512
        const double S1 = red[0][0], Q1 = red[1][0];
        const double m1 = S1 / nelem1;
        const double v1 = (Q1 - S1 * S1 / nelem1) / (nelem1 - 1.0);
        const double sd1 = sqrt(v1 > 0.0 ? v1 : 0.0);
        const float rs1f = (float)(1.0 / (sd1 + 1e-5));
        const float m1f = (float)m1;
        const double a1 = (double)rs1f;
        const double b1 = -(double)m1f * (double)rs1f;
        const double S2l = red[2][0], Q2l = red[3][0];
        const double S2h = red[4][0], Q2h = red[5][0];
        const double Sf = S2l + a1 * S2h + b1 * cnthi;
        const double Qf = Q2l + a1 * a1 * Q2h + 2.0 * a1 * b1 * S2h + b1 * b1 * cnthi;
        const double m2 = Sf / cnt2;
        const double v2 = (Qf - Sf * Sf / cnt2) / (cnt2 - 1.0);
        const double sd2 = sqrt(v2 > 0.0 ? v2 : 0.0);
        const double rs2 = 1.0 / (sd2 + 1e-5);
        stats4[0] = (float)rs2;                 // alpha_lo (c < 256)
        stats4[1] = (float)(-m2 * rs2);         // beta_lo
        stats4[2] = (float)(a1 * rs2);          // alpha_hi (c >= 256)
        stats4[3] = (float)((b1 - m2) * rs2);   // beta_hi
    }
}

// L5: level-2 write pass: grid (x=B, y=128 n-tiles, z=12 c-blocks). Gather raw
// inter rows, apply per-region affine, write TRANSPOSED via 64x64 LDS tile.
__global__ __launch_bounds__(256) void k_interp2_write(const float* __restrict__ pts,
                                                       const float* __restrict__ cand_d,
                                                       const int* __restrict__ cand_i,
                                                       const float* __restrict__ stats4,
                                                       float* __restrict__ out) {
    __shared__ float tile[64][65];
    __shared__ int   si[64][3];
    __shared__ float sw[64][3];
    const int b = blockIdx.x, nt = blockIdx.y, cc = blockIdx.z;
    const float alpha = (cc < 4) ? stats4[0] : stats4[2];
    const float beta  = (cc < 4) ? stats4[1] : stats4[3];
    const int n0 = nt * 64, c0 = cc * 64;
    const int tid = threadIdx.x;
    if (tid < 64) {
        const size_t pt = (size_t)b * 8192 + n0 + tid;
        dev_merge<12>(cand_d + pt * 12, cand_i + pt * 12,
                      si[tid][0], si[tid][1], si[tid][2],
                      sw[tid][0], sw[tid][1], sw[tid][2]);
    }
    __syncthreads();
    const float* pb = pts + (size_t)b * 2048 * 768 + c0;
    const int cl = tid & 63;
    const int pg = tid >> 6;
#pragma unroll
    for (int pass = 0; pass < 16; ++pass) {
        const int nl = pass * 4 + pg;
        const float v = (sw[nl][0] * pb[(size_t)si[nl][0] * 768 + cl]
                       + sw[nl][1] * pb[(size_t)si[nl][1] * 768 + cl])
                       + sw[nl][2] * pb[(size_t)si[nl][2] * 768 + cl];
        tile[nl][cl] = alpha * v + beta;
    }
    __syncthreads();
    float* ob = out + (size_t)b * 896 * 8192 + (size_t)(128 + c0) * 8192 + n0;
    const int tn = tid & 63, tc0 = tid >> 6;
#pragma unroll
    for (int pass = 0; pass < 16; ++pass) {
        const int tc = pass * 4 + tc0;
        ob[(size_t)tc * 8192 + tn] = tile[tn][tc];
    }
}

extern "C" void kernel_launch(void* const* d_in, const int* in_sizes, int n_in,
                              void* d_out, int out_size, void* d_ws, size_t ws_size,
                              hipStream_t stream) {
    const float* xyz0 = (const float*)d_in[0];
    const float* xyz1 = (const float*)d_in[1];
    const float* xyz2 = (const float*)d_in[2];
    const float* x0   = (const float*)d_in[3];
    const float* x1   = (const float*)d_in[4];
    const float* x2   = (const float*)d_in[5];
    float* out = (float*)d_out;
    char* ws = (char*)d_ws;

    size_t off = 0;
    auto alloc = [&](size_t bytes) {
        size_t o = off;
        off = (off + bytes + 255) & ~(size_t)255;
        return o;
    };
    float*  stats4    = (float*)(ws + alloc(4 * sizeof(float)));
    double* partials1 = (double*)(ws + alloc((size_t)1024 * 2 * sizeof(double)));
    double* partials2 = (double*)(ws + alloc((size_t)6144 * 2 * sizeof(double)));
    float*  pts1      = (float*)(ws + alloc((size_t)8 * 512 * 512 * 4));   // x2^T
    float*  inter     = (float*)(ws + alloc((size_t)8 * 2048 * 768 * 4));  // RAW [8,2048,768]
    float*  cand_d2   = (float*)(ws + alloc((size_t)65536 * 12 * 4));
    int*    cand_i2   = (int*)(ws + alloc((size_t)65536 * 12 * 4));
    float*  cand_d1   = (float*)(ws + alloc((size_t)16384 * 6 * 4));
    int*    cand_i1   = (int*)(ws + alloc((size_t)16384 * 6 * 4));

    // L1: knn2 | knn1 | copy0 | transB | transA
    k_front<<<14976, 256, 0, stream>>>(xyz0, xyz1, xyz2, x0, x1, x2,
                                       pts1, inter, out,
                                       cand_d2, cand_i2, cand_d1, cand_i1);
    // L2: level-1 fused raw write + partials1
    k_interp1_fused<<<dim3(8, 128), 256, 0, stream>>>(
        pts1, cand_d1, cand_i1, inter, partials1);
    // L3: level-2 raw stats -> partials2 (cb-major: first 2048 = c<256)
    k_interp_stats<<<dim3(8, 256, 3), 256, 0, stream>>>(
        inter, cand_d2, cand_i2, 8192, 2048, 768, partials2);
    // L4: combined finalize -> stats4
    k_fin_combined<<<1, 256, 0, stream>>>(partials1, 1024, partials2, 6144, 2048, stats4);
    // L5: level-2 write with per-region affine
    k_interp2_write<<<dim3(8, 128, 12), 256, 0, stream>>>(inter, cand_d2, cand_i2,
                                                          stats4, out);
}

// Round 16
// 175.575 us; speedup vs baseline: 1.2228x; 1.0104x over previous
//
#include <hip/hip_runtime.h>
#include <cstdint>
#include <math.h>

// ---------------------------------------------------------------------------
// Problem constants
//   B=8
//   level 1: fine xyz1 [8,2048,3], coarse xyz2 [8,512,3], x1 [8,256,2048], x2 [8,512,512]
//   level 2: fine xyz0 [8,8192,3], coarse xyz1 [8,2048,3], x0 [8,128,8192]
//   out [8, 896, 8192] f32
// 5-launch schedule (inter holds RAW level-1 interp; normalization deferred
// into write2 as a per-region affine alpha*v+beta):
//   L1 k_front         : knn2 | knn1 | copy0 | transB | transA
//   L2 k_interp1_fused : gather pts1 -> raw inter[:, :, 256:768] + partials1
//   L3 k_interp_stats  : gather raw inter -> partials2 (per-cb region split)
//   L4 k_fin_combined  : double reduce + affine correction -> {a,b}x{lo,hi}
//   L5 k_interp2_write : gather raw inter, out = a*v + b (per c-block a,b)
// Rules learned:
//   - no per-block agent-scope fences/atomics in hot kernels (R7)
//   - LDS-staged knn beats uniform VMEM scan at this occupancy (R9)
//   - knn scan needs >=2 waves/SIMD (512 blocks) (R11)
//   - LDS issue count is the knn floor (R13); 2 fine pts per LDS read
//   - out is write-once: nontemporal stores keep L2 for the gather sets
//     (builtin needs native vector type, not HIP_vector_type -- R15)
// ---------------------------------------------------------------------------

typedef float nt_float4 __attribute__((ext_vector_type(4)));

// Merge NC candidates (NC/3 chunks x sorted top-3, chunk-major => ascending
// index order within equal distances; strict < keeps the earlier candidate,
// matching top_k tie-breaking). Weights = normalized inverse distances.
template <int NC>
__device__ __forceinline__ void dev_merge(const float* __restrict__ cd,
                                          const int* __restrict__ ci,
                                          int& o0, int& o1, int& o2,
                                          float& w0, float& w1, float& w2) {
    float d0 = 1e30f, d1 = 1e30f, d2 = 1e30f;
    int j0 = 0, j1 = 0, j2 = 0;
#pragma unroll
    for (int k = 0; k < NC; ++k) {
        const float d = cd[k];
        const int s = ci[k];
        const bool lt0 = d < d0, lt1 = d < d1, lt2 = d < d2;
        d2 = lt1 ? d1 : (lt2 ? d : d2);
        j2 = lt1 ? j1 : (lt2 ? s : j2);
        d1 = lt0 ? d0 : (lt1 ? d : d1);
        j1 = lt0 ? j0 : (lt1 ? s : j1);
        d0 = lt0 ? d : d0;
        j0 = lt0 ? s : j0;
    }
    const float a = 1.0f / (d0 + 1e-8f);
    const float b = 1.0f / (d1 + 1e-8f);
    const float c = 1.0f / (d2 + 1e-8f);
    const float ws = (a + b) + c;
    o0 = j0; o1 = j1; o2 = j2;
    w0 = a / ws; w1 = b / ws; w2 = c / ws;
}

// Branchless sorted-top3 insert (bit-identical to sequential scan insert).
__device__ __forceinline__ void dev_ins3(float d, int s,
                                         float& d0, float& d1, float& d2,
                                         int& i0, int& i1, int& i2) {
    const bool lt0 = d < d0, lt1 = d < d1, lt2 = d < d2;
    d2 = lt1 ? d1 : (lt2 ? d : d2);
    i2 = lt1 ? i1 : (lt2 ? s : i2);
    d1 = lt0 ? d0 : (lt1 ? d : d1);
    i1 = lt0 ? i0 : (lt1 ? s : i1);
    d0 = lt0 ? d : d0;
    i0 = lt0 ? s : i0;
}

// kNN scan, 2 fine points per thread, batch-8, fully branchless.
// Coarse chunk staged in LDS; each ds_read_b128 feeds BOTH points' distance
// computations. Block covers 512 fine points: A = n0+tid, B = n0+256+tid.
// Distance form bit-matches reference: fmaf(-2,dot,psq+cw) == (psq+cw)-2*dot.
template <int CHUNK>
__device__ __forceinline__ void dev_knn2pt(const float* __restrict__ fine,
                                           const float* __restrict__ coarse,
                                           int N, int S, int nch,
                                           int b, int nb, int chunk, int tid,
                                           float4* __restrict__ lc,
                                           float* __restrict__ cand_d,
                                           int* __restrict__ cand_i) {
#pragma clang fp contract(off)
    const int s0 = chunk * CHUNK;
    const float* cb = coarse + ((size_t)b * S + s0) * 3;
    for (int s = tid; s < CHUNK; s += 256) {
        const float x = cb[3 * s], y = cb[3 * s + 1], z = cb[3 * s + 2];
        lc[s] = make_float4(x, y, z, (x * x + y * y) + z * z);
    }
    __syncthreads();
    const int na = nb * 512 + tid;
    const int nB = na + 256;
    const float* fa = fine + ((size_t)b * N + na) * 3;
    const float* fb = fine + ((size_t)b * N + nB) * 3;
    const float ax = fa[0], ay = fa[1], az = fa[2];
    const float bx = fb[0], by = fb[1], bz = fb[2];
    const float asq = (ax * ax + ay * ay) + az * az;
    const float bsq = (bx * bx + by * by) + bz * bz;
    float da0 = 1e30f, da1 = 1e30f, da2 = 1e30f;
    float db0 = 1e30f, db1 = 1e30f, db2 = 1e30f;
    int ia0 = 0, ia1 = 0, ia2 = 0;
    int ib0 = 0, ib1 = 0, ib2 = 0;
    for (int s8 = 0; s8 < CHUNK; s8 += 8) {
        float dA[8], dB[8];
#pragma unroll
        for (int u = 0; u < 8; ++u) {
            const float4 c = lc[s8 + u];
            dA[u] = fmaf(-2.0f, (ax * c.x + ay * c.y) + az * c.z, asq + c.w);
            dB[u] = fmaf(-2.0f, (bx * c.x + by * c.y) + bz * c.z, bsq + c.w);
        }
#pragma unroll
        for (int u = 0; u < 8; ++u) {
            dev_ins3(dA[u], s8 + u, da0, da1, da2, ia0, ia1, ia2);
            dev_ins3(dB[u], s8 + u, db0, db1, db2, ib0, ib1, ib2);
        }
    }
    const size_t pa = (((size_t)b * N + na) * nch + chunk) * 3;
    cand_d[pa] = da0; cand_d[pa + 1] = da1; cand_d[pa + 2] = da2;
    cand_i[pa] = s0 + ia0; cand_i[pa + 1] = s0 + ia1; cand_i[pa + 2] = s0 + ia2;
    const size_t pb = (((size_t)b * N + nB) * nch + chunk) * 3;
    cand_d[pb] = db0; cand_d[pb + 1] = db1; cand_d[pb + 2] = db2;
    cand_i[pb] = s0 + ib0; cand_i[pb + 1] = s0 + ib1; cand_i[pb + 2] = s0 + ib2;
}

// 1-pt/thread batch-8 branchless scan (level 1 -- scan work is trivial).
template <int CHUNK>
__device__ __forceinline__ void dev_knn1pt(const float* __restrict__ fine,
                                           const float* __restrict__ coarse,
                                           int N, int S, int nch,
                                           int b, int nb, int chunk, int tid,
                                           float4* __restrict__ lc,
                                           float* __restrict__ cand_d,
                                           int* __restrict__ cand_i) {
#pragma clang fp contract(off)
    const int s0 = chunk * CHUNK;
    const float* cb = coarse + ((size_t)b * S + s0) * 3;
    for (int s = tid; s < CHUNK; s += 256) {
        const float x = cb[3 * s], y = cb[3 * s + 1], z = cb[3 * s + 2];
        lc[s] = make_float4(x, y, z, (x * x + y * y) + z * z);
    }
    __syncthreads();
    const int n = nb * 256 + tid;
    const float* fp = fine + ((size_t)b * N + n) * 3;
    const float px = fp[0], py = fp[1], pz = fp[2];
    const float psq = (px * px + py * py) + pz * pz;
    float d0 = 1e30f, d1 = 1e30f, d2 = 1e30f;
    int i0 = 0, i1 = 0, i2 = 0;
    for (int s8 = 0; s8 < CHUNK; s8 += 8) {
        float dv[8];
#pragma unroll
        for (int u = 0; u < 8; ++u) {
            const float4 c = lc[s8 + u];
            dv[u] = fmaf(-2.0f, (px * c.x + py * c.y) + pz * c.z, psq + c.w);
        }
#pragma unroll
        for (int u = 0; u < 8; ++u) {
            dev_ins3(dv[u], s8 + u, d0, d1, d2, i0, i1, i2);
        }
    }
    const size_t p = (((size_t)b * N + n) * nch + chunk) * 3;
    cand_d[p] = d0; cand_d[p + 1] = d1; cand_d[p + 2] = d2;
    cand_i[p] = s0 + i0; cand_i[p + 1] = s0 + i1; cand_i[p + 2] = s0 + i2;
}

__device__ __forceinline__ void dev_transpose(const float* __restrict__ in,
                                              float* __restrict__ out,
                                              int C, long in_bs, long out_bs, int out_rs,
                                              int b, int rt, int ct, int tid,
                                              float* __restrict__ tile /*[32][33]*/) {
    const int r0 = rt * 32, c0 = ct * 32;
    const float* inb = in + (size_t)b * in_bs;
    float* outb = out + (size_t)b * out_bs;
    const int tx = tid & 31, ty = tid >> 5;   // 32 x 8
#pragma unroll
    for (int i = 0; i < 32; i += 8) {
        tile[(ty + i) * 33 + tx] = inb[(size_t)(r0 + ty + i) * C + (c0 + tx)];
    }
    __syncthreads();
#pragma unroll
    for (int i = 0; i < 32; i += 8) {
        outb[(size_t)(c0 + ty + i) * out_rs + (r0 + tx)] = tile[tx * 33 + (ty + i)];
    }
}

// L1: fused front. Blocks:
//   [0,512)        knn level 2, 2pt/thread (CHUNK=512, nch=4, 512 pts/block):
//                  b=id>>6, nb=id&15, chunk=(id>>4)&3
//   [512,640)      knn level 1, 1pt/thread (CHUNK=256, nch=2):
//                  t=id-512: b=t>>4, nb=t&7, chunk=(t>>3)&1
//   [640,8832)     copy0  x0 -> out[:,0:128,:]  (nontemporal out stores)
//   [8832,12928)   transB x1 [8,256,2048] -> inter[b][c][r] (rs=768)
//   [12928,14976)  transA x2 [8,512,512]  -> pts1 (rs=512)
__global__ __launch_bounds__(256) void k_front(const float* __restrict__ xyz0,
                                               const float* __restrict__ xyz1,
                                               const float* __restrict__ xyz2,
                                               const float* __restrict__ x0,
                                               const float* __restrict__ x1,
                                               const float* __restrict__ x2,
                                               float* __restrict__ pts1,
                                               float* __restrict__ inter,
                                               float* __restrict__ out,
                                               float* __restrict__ cand_d2,
                                               int* __restrict__ cand_i2,
                                               float* __restrict__ cand_d1,
                                               int* __restrict__ cand_i1) {
    __shared__ __align__(16) char smem[8192];    // union: lc (8K) | tile (4.2K)
    const int id = blockIdx.x;
    const int tid = threadIdx.x;
    if (id < 512) {
        dev_knn2pt<512>(xyz0, xyz1, 8192, 2048, 4,
                        id >> 6, id & 15, (id >> 4) & 3, tid,
                        (float4*)smem, cand_d2, cand_i2);
    } else if (id < 640) {
        const int t = id - 512;
        dev_knn1pt<256>(xyz1, xyz2, 2048, 512, 2,
                        t >> 4, t & 7, (t >> 3) & 1, tid,
                        (float4*)smem, cand_d1, cand_i1);
    } else if (id < 8832) {                      // copy0 (streaming out stores)
        const size_t i = (size_t)(id - 640) * 256 + tid;
        const size_t b = i >> 18;
        const size_t off = i & (((size_t)1 << 18) - 1);
        const nt_float4* src = (const nt_float4*)(x0 + b * (size_t)128 * 8192);
        nt_float4* dst = (nt_float4*)(out + b * (size_t)896 * 8192);
        __builtin_nontemporal_store(src[off], &dst[off]);
    } else if (id < 12928) {                     // transB
        const int t = id - 8832;
        const int ct = t & 63, rt = (t >> 6) & 7, b = t >> 9;
        dev_transpose(x1, inter, 2048, 256 * 2048, (long)2048 * 768, 768,
                      b, rt, ct, tid, (float*)smem);
    } else {                                     // transA
        const int t = id - 12928;
        const int ct = t & 15, rt = (t >> 4) & 15, b = t >> 8;
        dev_transpose(x2, pts1, 512, 512 * 512, 512 * 512, 512,
                      b, rt, ct, tid, (float*)smem);
    }
}

// L2: level-1 fused gather: write RAW interp to inter[:, :, 256:768] and
// accumulate double partials. Grid (x=8, y=128); 16 points/block.
__global__ __launch_bounds__(256) void k_interp1_fused(const float* __restrict__ pts,
                                                       const float* __restrict__ cand_d,
                                                       const int* __restrict__ cand_i,
                                                       float* __restrict__ inter,
                                                       double* __restrict__ partials1) {
    __shared__ int   si[16][3];
    __shared__ float sw[16][3];
    const int b = blockIdx.x, nb = blockIdx.y;
    const int n0 = nb * 16;
    const int tid = threadIdx.x;
    if (tid < 16) {
        const size_t pt = (size_t)b * 2048 + n0 + tid;
        dev_merge<6>(cand_d + pt * 6, cand_i + pt * 6,
                     si[tid][0], si[tid][1], si[tid][2],
                     sw[tid][0], sw[tid][1], sw[tid][2]);
    }
    __syncthreads();
    const float4* pb4 = (const float4*)(pts + (size_t)b * 512 * 512);
    const int pg = tid >> 6, f = tid & 63;
    double ls = 0.0, lq = 0.0;
#pragma unroll
    for (int g = 0; g < 4; ++g) {
        const int pl = g * 4 + pg;
        const size_t p = (size_t)b * 2048 + n0 + pl;
        const size_t r0 = (size_t)si[pl][0] * 128;
        const size_t r1 = (size_t)si[pl][1] * 128;
        const size_t r2 = (size_t)si[pl][2] * 128;
        const float w0 = sw[pl][0], w1 = sw[pl][1], w2 = sw[pl][2];
        float4* out4 = (float4*)(inter + p * 768 + 256);
#pragma unroll
        for (int k = 0; k < 2; ++k) {
            const int c = f + k * 64;
            const float4 a = pb4[r0 + c], d = pb4[r1 + c], e = pb4[r2 + c];
            float4 v;
            v.x = (w0 * a.x + w1 * d.x) + w2 * e.x;
            v.y = (w0 * a.y + w1 * d.y) + w2 * e.y;
            v.z = (w0 * a.z + w1 * d.z) + w2 * e.z;
            v.w = (w0 * a.w + w1 * d.w) + w2 * e.w;
            out4[c] = v;
            ls += (double)v.x + (double)v.y + (double)v.z + (double)v.w;
            lq += (double)v.x * v.x + (double)v.y * v.y
                + (double)v.z * v.z + (double)v.w * v.w;
        }
    }
    __shared__ double sa[256], sb[256];
    sa[tid] = ls; sb[tid] = lq; __syncthreads();
    for (int s = 128; s > 0; s >>= 1) {
        if (tid < s) { sa[tid] += sa[tid + s]; sb[tid] += sb[tid + s]; }
        __syncthreads();
    }
    if (tid == 0) {
        const size_t pl = (size_t)b * gridDim.y + nb;
        partials1[2 * pl] = sa[0]; partials1[2 * pl + 1] = sb[0];
    }
}

// L3: stats gather over raw inter; per-block double partials, cb-major layout
// so the finalize can split c<256 (cb=0) from c>=256 (cb=1,2).
// Grid (x=B, y=N/32, z=C/256); blockIdx.x = batch -> XCD-pinned L2 reuse.
__global__ __launch_bounds__(256) void k_interp_stats(const float* __restrict__ pts,
                                                      const float* __restrict__ cand_d,
                                                      const int* __restrict__ cand_i,
                                                      int N, int S, int C,
                                                      double* __restrict__ partials) {
    __shared__ int   si[32][3];
    __shared__ float sw[32][3];
    const int b = blockIdx.x, nb = blockIdx.y, cb = blockIdx.z;
    const int n0 = nb * 32;
    const int tid = threadIdx.x;
    if (tid < 32) {
        const size_t pt = (size_t)b * N + n0 + tid;
        dev_merge<12>(cand_d + pt * 12, cand_i + pt * 12,
                      si[tid][0], si[tid][1], si[tid][2],
                      sw[tid][0], sw[tid][1], sw[tid][2]);
    }
    __syncthreads();
    const int C4 = C >> 2;
    const float4* pbf = (const float4*)(pts + (size_t)b * S * C) + (cb * 64);
    const int f = tid & 63;
    const int pg = tid >> 6;
    double ls = 0.0, lq = 0.0;
#pragma unroll
    for (int g = 0; g < 8; ++g) {
        const int nl = g * 4 + pg;
        const size_t r0 = (size_t)si[nl][0] * C4;
        const size_t r1 = (size_t)si[nl][1] * C4;
        const size_t r2 = (size_t)si[nl][2] * C4;
        const float w0 = sw[nl][0], w1 = sw[nl][1], w2 = sw[nl][2];
        const float4 a = pbf[r0 + f], c = pbf[r1 + f], e = pbf[r2 + f];
        const float vx = (w0 * a.x + w1 * c.x) + w2 * e.x;
        const float vy = (w0 * a.y + w1 * c.y) + w2 * e.y;
        const float vz = (w0 * a.z + w1 * c.z) + w2 * e.z;
        const float vw = (w0 * a.w + w1 * c.w) + w2 * e.w;
        ls += (double)vx + (double)vy + (double)vz + (double)vw;
        lq += (double)vx * vx + (double)vy * vy + (double)vz * vz + (double)vw * vw;
    }
    __shared__ double sa[256], sb[256];
    sa[tid] = ls; sb[tid] = lq; __syncthreads();
    for (int s = 128; s > 0; s >>= 1) {
        if (tid < s) { sa[tid] += sa[tid + s]; sb[tid] += sb[tid + s]; }
        __syncthreads();
    }
    if (tid == 0) {
        const size_t pl = ((size_t)cb * gridDim.x + b) * gridDim.y + nb;
        partials[2 * pl] = sa[0]; partials[2 * pl + 1] = sb[0];
    }
}

// L4: combined finalize (1 block). Emits stats4 = {alpha_lo, beta_lo,
// alpha_hi, beta_hi}: out = alpha*v_raw + beta == (v_final - m2) * rs2.
__global__ __launch_bounds__(256) void k_fin_combined(const double* __restrict__ partials1,
                                                      int P1,
                                                      const double* __restrict__ partials2,
                                                      int P2, int P2lo,
                                                      float* __restrict__ stats4) {
    __shared__ double red[6][256];
    const int t = threadIdx.x;
    double s1 = 0.0, q1 = 0.0, s2l = 0.0, q2l = 0.0, s2h = 0.0, q2h = 0.0;
    for (int i = t; i < P1; i += 256) { s1 += partials1[2 * i]; q1 += partials1[2 * i + 1]; }
    for (int i = t; i < P2; i += 256) {
        const double s = partials2[2 * i], q = partials2[2 * i + 1];
        if (i < P2lo) { s2l += s; q2l += q; } else { s2h += s; q2h += q; }
    }
    red[0][t] = s1; red[1][t] = q1; red[2][t] = s2l;
    red[3][t] = q2l; red[4][t] = s2h; red[5][t] = q2h;
    __syncthreads();
    for (int s = 128; s > 0; s >>= 1) {
        if (t < s) {
#pragma unroll
            for (int r = 0; r < 6; ++r) red[r][t] += red[r][t + s];
        }
        __syncthreads();
    }
    if (t == 0) {
        const double nelem1 = 8388608.0;      // 8*2048*512
        const double cnt2   = 50331648.0;     // 8*8192*768
        const double cnthi  = 33554432.0;     // 8*8192*512
        const double S1 = red[0][0], Q1 = red[1][0];
        const double m1 = S1 / nelem1;
        const double v1 = (Q1 - S1 * S1 / nelem1) / (nelem1 - 1.0);
        const double sd1 = sqrt(v1 > 0.0 ? v1 : 0.0);
        const float rs1f = (float)(1.0 / (sd1 + 1e-5));
        const float m1f = (float)m1;
        const double a1 = (double)rs1f;
        const double b1 = -(double)m1f * (double)rs1f;
        const double S2l = red[2][0], Q2l = red[3][0];
        const double S2h = red[4][0], Q2h = red[5][0];
        const double Sf = S2l + a1 * S2h + b1 * cnthi;
        const double Qf = Q2l + a1 * a1 * Q2h + 2.0 * a1 * b1 * S2h + b1 * b1 * cnthi;
        const double m2 = Sf / cnt2;
        const double v2 = (Qf - Sf * Sf / cnt2) / (cnt2 - 1.0);
        const double sd2 = sqrt(v2 > 0.0 ? v2 : 0.0);
        const double rs2 = 1.0 / (sd2 + 1e-5);
        stats4[0] = (float)rs2;                 // alpha_lo (c < 256)
        stats4[1] = (float)(-m2 * rs2);         // beta_lo
        stats4[2] = (float)(a1 * rs2);          // alpha_hi (c >= 256)
        stats4[3] = (float)((b1 - m2) * rs2);   // beta_hi
    }
}

// L5: level-2 write pass: grid (x=B, y=128 n-tiles, z=12 c-blocks). Gather raw
// inter rows, apply per-region affine, write TRANSPOSED via 64x64 LDS tile.
// Out stores are nontemporal: out is never re-read, keep L2 for inter slices.
__global__ __launch_bounds__(256) void k_interp2_write(const float* __restrict__ pts,
                                                       const float* __restrict__ cand_d,
                                                       const int* __restrict__ cand_i,
                                                       const float* __restrict__ stats4,
                                                       float* __restrict__ out) {
    __shared__ float tile[64][65];
    __shared__ int   si[64][3];
    __shared__ float sw[64][3];
    const int b = blockIdx.x, nt = blockIdx.y, cc = blockIdx.z;
    const float alpha = (cc < 4) ? stats4[0] : stats4[2];
    const float beta  = (cc < 4) ? stats4[1] : stats4[3];
    const int n0 = nt * 64, c0 = cc * 64;
    const int tid = threadIdx.x;
    if (tid < 64) {
        const size_t pt = (size_t)b * 8192 + n0 + tid;
        dev_merge<12>(cand_d + pt * 12, cand_i + pt * 12,
                      si[tid][0], si[tid][1], si[tid][2],
                      sw[tid][0], sw[tid][1], sw[tid][2]);
    }
    __syncthreads();
    const float* pb = pts + (size_t)b * 2048 * 768 + c0;
    const int cl = tid & 63;
    const int pg = tid >> 6;
#pragma unroll
    for (int pass = 0; pass < 16; ++pass) {
        const int nl = pass * 4 + pg;
        const float v = (sw[nl][0] * pb[(size_t)si[nl][0] * 768 + cl]
                       + sw[nl][1] * pb[(size_t)si[nl][1] * 768 + cl])
                       + sw[nl][2] * pb[(size_t)si[nl][2] * 768 + cl];
        tile[nl][cl] = alpha * v + beta;
    }
    __syncthreads();
    float* ob = out + (size_t)b * 896 * 8192 + (size_t)(128 + c0) * 8192 + n0;
    const int tn = tid & 63, tc0 = tid >> 6;
#pragma unroll
    for (int pass = 0; pass < 16; ++pass) {
        const int tc = pass * 4 + tc0;
        __builtin_nontemporal_store(tile[tn][tc], &ob[(size_t)tc * 8192 + tn]);
    }
}

extern "C" void kernel_launch(void* const* d_in, const int* in_sizes, int n_in,
                              void* d_out, int out_size, void* d_ws, size_t ws_size,
                              hipStream_t stream) {
    const float* xyz0 = (const float*)d_in[0];
    const float* xyz1 = (const float*)d_in[1];
    const float* xyz2 = (const float*)d_in[2];
    const float* x0   = (const float*)d_in[3];
    const float* x1   = (const float*)d_in[4];
    const float* x2   = (const float*)d_in[5];
    float* out = (float*)d_out;
    char* ws = (char*)d_ws;

    size_t off = 0;
    auto alloc = [&](size_t bytes) {
        size_t o = off;
        off = (off + bytes + 255) & ~(size_t)255;
        return o;
    };
    float*  stats4    = (float*)(ws + alloc(4 * sizeof(float)));
    double* partials1 = (double*)(ws + alloc((size_t)1024 * 2 * sizeof(double)));
    double* partials2 = (double*)(ws + alloc((size_t)6144 * 2 * sizeof(double)));
    float*  pts1      = (float*)(ws + alloc((size_t)8 * 512 * 512 * 4));   // x2^T
    float*  inter     = (float*)(ws + alloc((size_t)8 * 2048 * 768 * 4));  // RAW [8,2048,768]
    float*  cand_d2   = (float*)(ws + alloc((size_t)65536 * 12 * 4));
    int*    cand_i2   = (int*)(ws + alloc((size_t)65536 * 12 * 4));
    float*  cand_d1   = (float*)(ws + alloc((size_t)16384 * 6 * 4));
    int*    cand_i1   = (int*)(ws + alloc((size_t)16384 * 6 * 4));

    // L1: knn2 | knn1 | copy0 | transB | transA
    k_front<<<14976, 256, 0, stream>>>(xyz0, xyz1, xyz2, x0, x1, x2,
                                       pts1, inter, out,
                                       cand_d2, cand_i2, cand_d1, cand_i1);
    // L2: level-1 fused raw write + partials1
    k_interp1_fused<<<dim3(8, 128), 256, 0, stream>>>(
        pts1, cand_d1, cand_i1, inter, partials1);
    // L3: level-2 raw stats -> partials2 (cb-major: first 2048 = c<256)
    k_interp_stats<<<dim3(8, 256, 3), 256, 0, stream>>>(
        inter, cand_d2, cand_i2, 8192, 2048, 768, partials2);
    // L4: combined finalize -> stats4
    k_fin_combined<<<1, 256, 0, stream>>>(partials1, 1024, partials2, 6144, 2048, stats4);
    // L5: level-2 write with per-region affine
    k_interp2_write<<<dim3(8, 128, 12), 256, 0, stream>>>(inter, cand_d2, cand_i2,
                                                          stats4, out);
}